// Round 7
// baseline (949.283 us; speedup 1.0000x reference)
//
#include <hip/hip_runtime.h>

// GIN: h1 = relu((scatter_add(x) + (1+eps0)*x) @ W0^T)
//      h2 = relu((scatter_add(h1) + (1+eps1)*h1) @ W1^T)
//      out = (h1 @ Wm^T + h2) / 2
//
// R7: node-tiled matvec (NT=4): wave gathers 4 nodes' agg rows, then one
// matvec pass amortizes W LDS reads 4x (W traffic was ~32KB/node in final =
// ~49us of LDS BW). Group-of-16 gather partials reduced via __shfl_xor(16/32)
// (P buffer gone -> gin at 32 waves/CU). CSR build: hist_rank 16 edges/thr,
// fill_rank 8 edges/thr.

// ================================================================ CSR build
__global__ __launch_bounds__(256) void zero_int_kernel(int* __restrict__ p, int n)
{
    int i = blockIdx.x * blockDim.x + threadIdx.x;
    int stride = gridDim.x * blockDim.x;
    for (; i < n; i += stride) p[i] = 0;
}

// rank-capturing histogram: 16 edges/thread (16 outstanding atomic round-trips)
__global__ __launch_bounds__(256) void hist_rank_kernel(
    const int* __restrict__ dst, int* __restrict__ deg,
    int* __restrict__ rank, int E)
{
    int base = (blockIdx.x * blockDim.x + threadIdx.x) * 16;
    if (base + 15 < E) {
        int4 a = *(const int4*)&dst[base];
        int4 b = *(const int4*)&dst[base + 4];
        int4 c = *(const int4*)&dst[base + 8];
        int4 d = *(const int4*)&dst[base + 12];
        int r0 = atomicAdd(&deg[a.x], 1);
        int r1 = atomicAdd(&deg[a.y], 1);
        int r2 = atomicAdd(&deg[a.z], 1);
        int r3 = atomicAdd(&deg[a.w], 1);
        int r4 = atomicAdd(&deg[b.x], 1);
        int r5 = atomicAdd(&deg[b.y], 1);
        int r6 = atomicAdd(&deg[b.z], 1);
        int r7 = atomicAdd(&deg[b.w], 1);
        int r8 = atomicAdd(&deg[c.x], 1);
        int r9 = atomicAdd(&deg[c.y], 1);
        int rA = atomicAdd(&deg[c.z], 1);
        int rB = atomicAdd(&deg[c.w], 1);
        int rC = atomicAdd(&deg[d.x], 1);
        int rD = atomicAdd(&deg[d.y], 1);
        int rE = atomicAdd(&deg[d.z], 1);
        int rF = atomicAdd(&deg[d.w], 1);
        *(int4*)&rank[base]      = make_int4(r0, r1, r2, r3);
        *(int4*)&rank[base + 4]  = make_int4(r4, r5, r6, r7);
        *(int4*)&rank[base + 8]  = make_int4(r8, r9, rA, rB);
        *(int4*)&rank[base + 12] = make_int4(rC, rD, rE, rF);
    } else {
        for (int e = base; e < E; ++e) rank[e] = atomicAdd(&deg[dst[e]], 1);
    }
}

__global__ __launch_bounds__(256) void hist_kernel(
    const int* __restrict__ dst, int* __restrict__ deg, int E)
{
    int e4 = (blockIdx.x * blockDim.x + threadIdx.x) * 4;
    if (e4 + 3 < E) {
        int4 d = *(const int4*)&dst[e4];
        atomicAdd(&deg[d.x], 1);
        atomicAdd(&deg[d.y], 1);
        atomicAdd(&deg[d.z], 1);
        atomicAdd(&deg[d.w], 1);
    } else {
        for (int e = e4; e < E; ++e) atomicAdd(&deg[dst[e]], 1);
    }
}

__global__ __launch_bounds__(256) void scanA_kernel(
    const int* __restrict__ deg, int* __restrict__ off,
    int* __restrict__ bsum, int n)
{
    __shared__ int tmp[256];
    int t = threadIdx.x;
    int base = blockIdx.x * 1024 + t * 4;
    int v0 = 0, v1 = 0, v2 = 0, v3 = 0;
    if (base + 3 < n) {
        int4 q = *(const int4*)&deg[base];
        v0 = q.x; v1 = q.y; v2 = q.z; v3 = q.w;
    } else {
        if (base + 0 < n) v0 = deg[base + 0];
        if (base + 1 < n) v1 = deg[base + 1];
        if (base + 2 < n) v2 = deg[base + 2];
    }
    int tot = v0 + v1 + v2 + v3;
    tmp[t] = tot;
    __syncthreads();
    for (int d = 1; d < 256; d <<= 1) {
        int x = (t >= d) ? tmp[t - d] : 0;
        __syncthreads();
        tmp[t] += x;
        __syncthreads();
    }
    int incl = tmp[t];
    int p = incl - tot;
    if (base + 0 < n) off[base + 0] = p;
    if (base + 1 < n) off[base + 1] = p + v0;
    if (base + 2 < n) off[base + 2] = p + v0 + v1;
    if (base + 3 < n) off[base + 3] = p + v0 + v1 + v2;
    if (t == 255) bsum[blockIdx.x] = incl;
}

__global__ __launch_bounds__(256) void scanB_kernel(int* __restrict__ bsum, int nb)
{
    __shared__ int tmp[256];
    int t = threadIdx.x;
    int v = (t < nb) ? bsum[t] : 0;
    tmp[t] = v;
    __syncthreads();
    for (int d = 1; d < 256; d <<= 1) {
        int x = (t >= d) ? tmp[t - d] : 0;
        __syncthreads();
        tmp[t] += x;
        __syncthreads();
    }
    if (t < nb) bsum[t] = tmp[t] - v;
}

__global__ __launch_bounds__(256) void scanC_kernel(
    int* __restrict__ off, int* __restrict__ cursor,
    const int* __restrict__ bsum, int n, int E)
{
    int t = threadIdx.x;
    int add = bsum[blockIdx.x];
    int base = blockIdx.x * 1024 + t * 4;
#pragma unroll
    for (int q = 0; q < 4; ++q) {
        int idx = base + q;
        if (idx < n) {
            int v = off[idx] + add;
            off[idx] = v;
            if (cursor) cursor[idx] = v;
        }
    }
    if (blockIdx.x == 0 && t == 0) off[n] = E;
}

// atomic-free fill, 8 edges/thread
__global__ __launch_bounds__(256) void fill_rank_kernel(
    const int* __restrict__ src, const int* __restrict__ dst,
    const int* __restrict__ rank, const int* __restrict__ off,
    int* __restrict__ bucket, int E)
{
    int base = (blockIdx.x * blockDim.x + threadIdx.x) * 8;
    if (base + 7 < E) {
        int4 d0 = *(const int4*)&dst[base];
        int4 d1 = *(const int4*)&dst[base + 4];
        int4 r0 = *(const int4*)&rank[base];
        int4 r1 = *(const int4*)&rank[base + 4];
        int4 s0 = *(const int4*)&src[base];
        int4 s1 = *(const int4*)&src[base + 4];
        bucket[off[d0.x] + r0.x] = s0.x;
        bucket[off[d0.y] + r0.y] = s0.y;
        bucket[off[d0.z] + r0.z] = s0.z;
        bucket[off[d0.w] + r0.w] = s0.w;
        bucket[off[d1.x] + r1.x] = s1.x;
        bucket[off[d1.y] + r1.y] = s1.y;
        bucket[off[d1.z] + r1.z] = s1.z;
        bucket[off[d1.w] + r1.w] = s1.w;
    } else {
        for (int e = base; e < E; ++e) bucket[off[dst[e]] + rank[e]] = src[e];
    }
}

__global__ __launch_bounds__(256) void fill_kernel(
    const int* __restrict__ src, const int* __restrict__ dst,
    int* __restrict__ cursor, int* __restrict__ bucket, int E)
{
    int e = blockIdx.x * blockDim.x + threadIdx.x;
    if (e < E) {
        int d = dst[e];
        int p = atomicAdd(&cursor[d], 1);
        bucket[p] = src[e];
    }
}

// ================================================================ fused gather + matvec
#define WPB 8  // waves per 512-thread block
#define NT  4  // nodes per wave per iteration

__device__ __forceinline__ float dot4(float4 a, float4 b)
{
    return a.x * b.x + a.y * b.y + a.z * b.z + a.w * b.w;
}

// Gather one node's agg row (group g of 16 lanes handles every 4th edge as
// float4); returns reduced row chunk [l16*4..l16*4+3] in all lanes.
__device__ __forceinline__ float4 gather_row(
    const float* __restrict__ h, const int* __restrict__ bucket,
    int beg, int end, int g, int l16, float4 init)
{
    float4 acc4 = init;
    int j = beg;
    for (; j + 8 <= end; j += 8) {
        int sa = bucket[j + g];
        int sb = bucket[j + 4 + g];
        float4 va = *(const float4*)&h[(size_t)sa * 64 + l16 * 4];
        float4 vb = *(const float4*)&h[(size_t)sb * 64 + l16 * 4];
        acc4.x += va.x + vb.x;
        acc4.y += va.y + vb.y;
        acc4.z += va.z + vb.z;
        acc4.w += va.w + vb.w;
    }
    if (j + 4 <= end) {
        int sa = bucket[j + g];
        float4 va = *(const float4*)&h[(size_t)sa * 64 + l16 * 4];
        acc4.x += va.x; acc4.y += va.y; acc4.z += va.z; acc4.w += va.w;
        j += 4;
    }
    if (j < end) {
        int jj = j + g;
        int sc = bucket[(jj < end) ? jj : (end - 1)];
        float m = (jj < end) ? 1.0f : 0.0f;
        float4 vc = *(const float4*)&h[(size_t)sc * 64 + l16 * 4];
        acc4.x = fmaf(vc.x, m, acc4.x);
        acc4.y = fmaf(vc.y, m, acc4.y);
        acc4.z = fmaf(vc.z, m, acc4.z);
        acc4.w = fmaf(vc.w, m, acc4.w);
    }
    // reduce across the 4 groups: xor-16 then xor-32
    acc4.x += __shfl_xor(acc4.x, 16, 64);
    acc4.y += __shfl_xor(acc4.y, 16, 64);
    acc4.z += __shfl_xor(acc4.z, 16, 64);
    acc4.w += __shfl_xor(acc4.w, 16, 64);
    acc4.x += __shfl_xor(acc4.x, 32, 64);
    acc4.y += __shfl_xor(acc4.y, 32, 64);
    acc4.z += __shfl_xor(acc4.z, 32, 64);
    acc4.w += __shfl_xor(acc4.w, 32, 64);
    return acc4;
}

// layer kernel: out = relu((agg + (1+eps)*self) @ W^T)
__global__ __launch_bounds__(512) void fused_gin_kernel(
    const float* __restrict__ h, const int* __restrict__ off,
    const int* __restrict__ bucket, const float* __restrict__ W,
    const float* __restrict__ eps, float* __restrict__ out, int n)
{
    __shared__ float Ws[64][68];            // W row-major, padded
    __shared__ float rowbuf[WPB][NT][64];   // agg rows for NT nodes
    int tid = threadIdx.x;
    for (int idx = tid; idx < 4096; idx += 512) Ws[idx >> 6][idx & 63] = W[idx];
    __syncthreads();
    float s = 1.0f + eps[0];
    int lane = tid & 63;
    int w = tid >> 6;
    int l16 = lane & 15;
    int g = lane >> 4;
    int stride = gridDim.x * WPB * NT;
    for (int i0 = (blockIdx.x * WPB + w) * NT; i0 < n; i0 += stride) {
#pragma unroll
        for (int t = 0; t < NT; ++t) {
            int i = i0 + t;
            if (i >= n) break;
            float4 init = make_float4(0.f, 0.f, 0.f, 0.f);
            if (g == 0) {
                float4 self4 = *(const float4*)&h[(size_t)i * 64 + l16 * 4];
                init = make_float4(s * self4.x, s * self4.y, s * self4.z, s * self4.w);
            }
            int2 be = *(const int2*)&off[i];
            int beg = __builtin_amdgcn_readfirstlane(be.x);
            int end = __builtin_amdgcn_readfirstlane(be.y);
            float4 red = gather_row(h, bucket, beg, end, g, l16, init);
            if (g == 0) *(float4*)&rowbuf[w][t][l16 * 4] = red;
        }
        __builtin_amdgcn_wave_barrier();
        const float4* wrow = (const float4*)&Ws[lane][0];
        float o[NT] = {0.f, 0.f, 0.f, 0.f};
#pragma unroll
        for (int k4 = 0; k4 < 16; ++k4) {
            float4 ww = wrow[k4];
#pragma unroll
            for (int t = 0; t < NT; ++t) {
                float4 rr = *(const float4*)&rowbuf[w][t][k4 * 4];
                o[t] += dot4(ww, rr);
            }
        }
#pragma unroll
        for (int t = 0; t < NT; ++t) {
            int i = i0 + t;
            if (i < n) out[(size_t)i * 64 + lane] = fmaxf(o[t], 0.f);
        }
        __builtin_amdgcn_wave_barrier();
    }
}

// final: out[i] = ( relu(agg(h1) @ W1^T) + h1[i] @ Wm^T ) / 2
__global__ __launch_bounds__(512) void fused_final_csr_kernel(
    const float* __restrict__ h1, const int* __restrict__ off,
    const int* __restrict__ bucket, const float* __restrict__ W1,
    const float* __restrict__ Wm, const float* __restrict__ eps,
    float* __restrict__ out, int n)
{
    __shared__ float W1s[64][68];
    __shared__ float Wms[64][68];
    __shared__ float rowbuf[WPB][NT][64];
    __shared__ float selfbuf[WPB][NT][64];
    int tid = threadIdx.x;
    for (int idx = tid; idx < 4096; idx += 512) {
        W1s[idx >> 6][idx & 63] = W1[idx];
        Wms[idx >> 6][idx & 63] = Wm[idx];
    }
    __syncthreads();
    float s = 1.0f + eps[0];
    int lane = tid & 63;
    int w = tid >> 6;
    int l16 = lane & 15;
    int g = lane >> 4;
    int stride = gridDim.x * WPB * NT;
    for (int i0 = (blockIdx.x * WPB + w) * NT; i0 < n; i0 += stride) {
#pragma unroll
        for (int t = 0; t < NT; ++t) {
            int i = i0 + t;
            if (i >= n) break;
            float4 init = make_float4(0.f, 0.f, 0.f, 0.f);
            if (g == 0) {
                float4 self4 = *(const float4*)&h1[(size_t)i * 64 + l16 * 4];
                *(float4*)&selfbuf[w][t][l16 * 4] = self4;
                init = make_float4(s * self4.x, s * self4.y, s * self4.z, s * self4.w);
            }
            int2 be = *(const int2*)&off[i];
            int beg = __builtin_amdgcn_readfirstlane(be.x);
            int end = __builtin_amdgcn_readfirstlane(be.y);
            float4 red = gather_row(h1, bucket, beg, end, g, l16, init);
            if (g == 0) *(float4*)&rowbuf[w][t][l16 * 4] = red;
        }
        __builtin_amdgcn_wave_barrier();
        const float4* w1row = (const float4*)&W1s[lane][0];
        const float4* wmrow = (const float4*)&Wms[lane][0];
        float o1[NT] = {0.f, 0.f, 0.f, 0.f};
        float o2[NT] = {0.f, 0.f, 0.f, 0.f};
#pragma unroll
        for (int k4 = 0; k4 < 16; ++k4) {
            float4 w1v = w1row[k4];
            float4 wmv = wmrow[k4];
#pragma unroll
            for (int t = 0; t < NT; ++t) {
                float4 rr = *(const float4*)&rowbuf[w][t][k4 * 4];
                float4 sv = *(const float4*)&selfbuf[w][t][k4 * 4];
                o1[t] += dot4(w1v, rr);
                o2[t] += dot4(wmv, sv);
            }
        }
#pragma unroll
        for (int t = 0; t < NT; ++t) {
            int i = i0 + t;
            if (i < n) out[(size_t)i * 64 + lane] = (fmaxf(o1[t], 0.f) + o2[t]) * 0.5f;
        }
        __builtin_amdgcn_wave_barrier();
    }
}

// ================================================================ R1 fallback (atomic scatter)
__global__ __launch_bounds__(256) void init_scale_kernel(
    const float* __restrict__ h, const float* __restrict__ eps,
    float* __restrict__ agg, int total4)
{
    float s = 1.0f + eps[0];
    int i = blockIdx.x * blockDim.x + threadIdx.x;
    int stride = gridDim.x * blockDim.x;
    const float4* h4 = (const float4*)h;
    float4* a4 = (float4*)agg;
    for (; i < total4; i += stride) {
        float4 v = h4[i];
        v.x *= s; v.y *= s; v.z *= s; v.w *= s;
        a4[i] = v;
    }
}

__global__ __launch_bounds__(256) void scatter_kernel(
    const float* __restrict__ h, const int* __restrict__ src,
    const int* __restrict__ dst, float* __restrict__ agg, int E)
{
    int lane = threadIdx.x & 63;
    int e = blockIdx.x * 4 + (threadIdx.x >> 6);
    if (e >= E) return;
    int s = src[e];
    int d = dst[e];
    atomicAdd(&agg[(size_t)d * 64 + lane], h[(size_t)s * 64 + lane]);
}

__global__ __launch_bounds__(256) void gemm_relu_kernel(
    const float* __restrict__ A, const float* __restrict__ W,
    float* __restrict__ out, int n)
{
    __shared__ float Wt[64][65];
    __shared__ float rowbuf[4][64];
    int tid = threadIdx.x;
    for (int i = tid; i < 4096; i += 256) Wt[i & 63][i >> 6] = W[i];
    __syncthreads();
    int lane = tid & 63;
    int w = tid >> 6;
    int wavesTotal = gridDim.x * 4;
    for (int i = blockIdx.x * 4 + w; i < n; i += wavesTotal) {
        rowbuf[w][lane] = A[(size_t)i * 64 + lane];
        __builtin_amdgcn_wave_barrier();
        float o = 0.f;
#pragma unroll
        for (int k = 0; k < 64; ++k) o += rowbuf[w][k] * Wt[k][lane];
        out[(size_t)i * 64 + lane] = fmaxf(o, 0.f);
        __builtin_amdgcn_wave_barrier();
    }
}

__global__ __launch_bounds__(256) void final_kernel(
    const float* __restrict__ Agg, const float* __restrict__ H1,
    const float* __restrict__ W1, const float* __restrict__ Wm,
    float* __restrict__ out, int n)
{
    __shared__ float W1t[64][65];
    __shared__ float Wmt[64][65];
    __shared__ float rowbuf[4][64];
    __shared__ float selfbuf[4][64];
    int tid = threadIdx.x;
    for (int i = tid; i < 4096; i += 256) {
        W1t[i & 63][i >> 6] = W1[i];
        Wmt[i & 63][i >> 6] = Wm[i];
    }
    __syncthreads();
    int lane = tid & 63;
    int w = tid >> 6;
    int wavesTotal = gridDim.x * 4;
    for (int i = blockIdx.x * 4 + w; i < n; i += wavesTotal) {
        rowbuf[w][lane] = Agg[(size_t)i * 64 + lane];
        selfbuf[w][lane] = H1[(size_t)i * 64 + lane];
        __builtin_amdgcn_wave_barrier();
        float o1 = 0.f, o2 = 0.f;
#pragma unroll
        for (int k = 0; k < 64; ++k) {
            o1 += rowbuf[w][k] * W1t[k][lane];
            o2 += selfbuf[w][k] * Wmt[k][lane];
        }
        out[(size_t)i * 64 + lane] = (fmaxf(o1, 0.f) + o2) * 0.5f;
        __builtin_amdgcn_wave_barrier();
    }
}

// ================================================================ launch
extern "C" void kernel_launch(void* const* d_in, const int* in_sizes, int n_in,
                              void* d_out, int out_size, void* d_ws, size_t ws_size,
                              hipStream_t stream)
{
    const float* x    = (const float*)d_in[0];
    const int*   ei   = (const int*)d_in[1];
    const float* W0   = (const float*)d_in[2];
    const float* eps0 = (const float*)d_in[3];
    const float* W1   = (const float*)d_in[4];
    const float* eps1 = (const float*)d_in[5];
    const float* Wm   = (const float*)d_in[6];
    float* out = (float*)d_out;

    int n = in_sizes[0] / 64;   // 100000
    int E = in_sizes[1] / 2;    // 1600000
    const int* src = ei;
    const int* dst = ei + E;

    auto align1k = [](size_t v) { return (v + 1023) & ~(size_t)1023; };
    size_t h1_off     = 0;
    size_t off_off    = align1k(h1_off + (size_t)n * 64 * 4);
    size_t deg_off    = align1k(off_off + (size_t)(n + 1) * 4);
    size_t cursor_off = align1k(deg_off + (size_t)n * 4);
    size_t bsum_off   = align1k(cursor_off + (size_t)n * 4);
    size_t bucket_off = align1k(bsum_off + 256 * 4);
    size_t rank_off   = align1k(bucket_off + (size_t)E * 4);
    size_t need_B     = rank_off;                  // ~33.2 MB
    size_t need_A     = rank_off + (size_t)E * 4;  // ~39.6 MB

    int nb = (n + 1023) / 1024;
    int e4Blocks  = (E + 1023) / 1024;
    int e8Blocks  = (E + 2047) / 2048;
    int e16Blocks = (E + 4095) / 4096;

    if (ws_size >= need_B) {
        float* h1    = (float*)((char*)d_ws + h1_off);
        int* off     = (int*)((char*)d_ws + off_off);
        int* deg     = (int*)((char*)d_ws + deg_off);
        int* cursor  = (int*)((char*)d_ws + cursor_off);
        int* bsum    = (int*)((char*)d_ws + bsum_off);
        int* bucket  = (int*)((char*)d_ws + bucket_off);
        int* rank    = (int*)((char*)d_ws + rank_off);

        zero_int_kernel<<<256, 256, 0, stream>>>(deg, n);
        if (ws_size >= need_A) {
            hist_rank_kernel<<<e16Blocks, 256, 0, stream>>>(dst, deg, rank, E);
            scanA_kernel<<<nb, 256, 0, stream>>>(deg, off, bsum, n);
            scanB_kernel<<<1, 256, 0, stream>>>(bsum, nb);
            scanC_kernel<<<nb, 256, 0, stream>>>(off, (int*)nullptr, bsum, n, E);
            fill_rank_kernel<<<e8Blocks, 256, 0, stream>>>(src, dst, rank, off, bucket, E);
        } else {
            hist_kernel<<<e4Blocks, 256, 0, stream>>>(dst, deg, E);
            scanA_kernel<<<nb, 256, 0, stream>>>(deg, off, bsum, n);
            scanB_kernel<<<1, 256, 0, stream>>>(bsum, nb);
            scanC_kernel<<<nb, 256, 0, stream>>>(off, cursor, bsum, n, E);
            fill_kernel<<<(E + 255) / 256, 256, 0, stream>>>(src, dst, cursor, bucket, E);
        }

        // gin: 25KB LDS -> 4 blocks/CU (32 waves, 100%); grid 1024 = 4/CU
        fused_gin_kernel<<<1024, 512, 0, stream>>>(x, off, bucket, W0, eps0, h1, n);
        // final: 50KB LDS -> 3 blocks/CU; grid 768 = 3/CU
        fused_final_csr_kernel<<<768, 512, 0, stream>>>(h1, off, bucket, W1, Wm, eps1, out, n);
    } else {
        float* agg = (float*)d_ws;
        float* h1  = out;
        int total4 = n * 16;
        int scatterBlocks = (E + 3) / 4;

        init_scale_kernel<<<2048, 256, 0, stream>>>(x, eps0, agg, total4);
        scatter_kernel<<<scatterBlocks, 256, 0, stream>>>(x, src, dst, agg, E);
        gemm_relu_kernel<<<2048, 256, 0, stream>>>(agg, W0, h1, n);
        init_scale_kernel<<<2048, 256, 0, stream>>>(h1, eps1, agg, total4);
        scatter_kernel<<<scatterBlocks, 256, 0, stream>>>(h1, src, dst, agg, E);
        final_kernel<<<2048, 256, 0, stream>>>(agg, h1, W1, Wm, out, n);
    }
}

// Round 8
// 311.934 us; speedup vs baseline: 3.0432x; 3.0432x over previous
//
#include <hip/hip_runtime.h>

// GIN: h1 = relu((scatter_add(x) + (1+eps0)*x) @ W0^T)
//      h2 = relu((scatter_add(h1) + (1+eps1)*h1) @ W1^T)
//      out = (h1 @ Wm^T + h2) / 2
//
// R8: R7's NT=4 node-tiling, fixed. R7 regressed (949us, WRITE 1.65GB) because
// `break` inside #pragma unroll blocked unrolling -> o[t]/rowbuf state became
// runtime-indexed -> scratch spills + occupancy collapse (rule #20). R8 makes
// all hot-path indexing compile-time BY CONSTRUCTION: wave-uniform full-group
// test, hand-unrolled x4 gather (macro with literal T), named accumulators
// o1_0..o1_3. Tail = one-node-at-a-time (R6-proven shape; never runs for
// n%4==0). CSR build unchanged (R5/R7-proven).

// ================================================================ CSR build
__global__ __launch_bounds__(256) void zero_int_kernel(int* __restrict__ p, int n)
{
    int i = blockIdx.x * blockDim.x + threadIdx.x;
    int stride = gridDim.x * blockDim.x;
    for (; i < n; i += stride) p[i] = 0;
}

__global__ __launch_bounds__(256) void hist_rank_kernel(
    const int* __restrict__ dst, int* __restrict__ deg,
    int* __restrict__ rank, int E)
{
    int base = (blockIdx.x * blockDim.x + threadIdx.x) * 16;
    if (base + 15 < E) {
        int4 a = *(const int4*)&dst[base];
        int4 b = *(const int4*)&dst[base + 4];
        int4 c = *(const int4*)&dst[base + 8];
        int4 d = *(const int4*)&dst[base + 12];
        int r0 = atomicAdd(&deg[a.x], 1);
        int r1 = atomicAdd(&deg[a.y], 1);
        int r2 = atomicAdd(&deg[a.z], 1);
        int r3 = atomicAdd(&deg[a.w], 1);
        int r4 = atomicAdd(&deg[b.x], 1);
        int r5 = atomicAdd(&deg[b.y], 1);
        int r6 = atomicAdd(&deg[b.z], 1);
        int r7 = atomicAdd(&deg[b.w], 1);
        int r8 = atomicAdd(&deg[c.x], 1);
        int r9 = atomicAdd(&deg[c.y], 1);
        int rA = atomicAdd(&deg[c.z], 1);
        int rB = atomicAdd(&deg[c.w], 1);
        int rC = atomicAdd(&deg[d.x], 1);
        int rD = atomicAdd(&deg[d.y], 1);
        int rE = atomicAdd(&deg[d.z], 1);
        int rF = atomicAdd(&deg[d.w], 1);
        *(int4*)&rank[base]      = make_int4(r0, r1, r2, r3);
        *(int4*)&rank[base + 4]  = make_int4(r4, r5, r6, r7);
        *(int4*)&rank[base + 8]  = make_int4(r8, r9, rA, rB);
        *(int4*)&rank[base + 12] = make_int4(rC, rD, rE, rF);
    } else {
        for (int e = base; e < E; ++e) rank[e] = atomicAdd(&deg[dst[e]], 1);
    }
}

__global__ __launch_bounds__(256) void hist_kernel(
    const int* __restrict__ dst, int* __restrict__ deg, int E)
{
    int e4 = (blockIdx.x * blockDim.x + threadIdx.x) * 4;
    if (e4 + 3 < E) {
        int4 d = *(const int4*)&dst[e4];
        atomicAdd(&deg[d.x], 1);
        atomicAdd(&deg[d.y], 1);
        atomicAdd(&deg[d.z], 1);
        atomicAdd(&deg[d.w], 1);
    } else {
        for (int e = e4; e < E; ++e) atomicAdd(&deg[dst[e]], 1);
    }
}

__global__ __launch_bounds__(256) void scanA_kernel(
    const int* __restrict__ deg, int* __restrict__ off,
    int* __restrict__ bsum, int n)
{
    __shared__ int tmp[256];
    int t = threadIdx.x;
    int base = blockIdx.x * 1024 + t * 4;
    int v0 = 0, v1 = 0, v2 = 0, v3 = 0;
    if (base + 3 < n) {
        int4 q = *(const int4*)&deg[base];
        v0 = q.x; v1 = q.y; v2 = q.z; v3 = q.w;
    } else {
        if (base + 0 < n) v0 = deg[base + 0];
        if (base + 1 < n) v1 = deg[base + 1];
        if (base + 2 < n) v2 = deg[base + 2];
    }
    int tot = v0 + v1 + v2 + v3;
    tmp[t] = tot;
    __syncthreads();
    for (int d = 1; d < 256; d <<= 1) {
        int x = (t >= d) ? tmp[t - d] : 0;
        __syncthreads();
        tmp[t] += x;
        __syncthreads();
    }
    int incl = tmp[t];
    int p = incl - tot;
    if (base + 0 < n) off[base + 0] = p;
    if (base + 1 < n) off[base + 1] = p + v0;
    if (base + 2 < n) off[base + 2] = p + v0 + v1;
    if (base + 3 < n) off[base + 3] = p + v0 + v1 + v2;
    if (t == 255) bsum[blockIdx.x] = incl;
}

__global__ __launch_bounds__(256) void scanB_kernel(int* __restrict__ bsum, int nb)
{
    __shared__ int tmp[256];
    int t = threadIdx.x;
    int v = (t < nb) ? bsum[t] : 0;
    tmp[t] = v;
    __syncthreads();
    for (int d = 1; d < 256; d <<= 1) {
        int x = (t >= d) ? tmp[t - d] : 0;
        __syncthreads();
        tmp[t] += x;
        __syncthreads();
    }
    if (t < nb) bsum[t] = tmp[t] - v;
}

__global__ __launch_bounds__(256) void scanC_kernel(
    int* __restrict__ off, int* __restrict__ cursor,
    const int* __restrict__ bsum, int n, int E)
{
    int t = threadIdx.x;
    int add = bsum[blockIdx.x];
    int base = blockIdx.x * 1024 + t * 4;
#pragma unroll
    for (int q = 0; q < 4; ++q) {
        int idx = base + q;
        if (idx < n) {
            int v = off[idx] + add;
            off[idx] = v;
            if (cursor) cursor[idx] = v;
        }
    }
    if (blockIdx.x == 0 && t == 0) off[n] = E;
}

__global__ __launch_bounds__(256) void fill_rank_kernel(
    const int* __restrict__ src, const int* __restrict__ dst,
    const int* __restrict__ rank, const int* __restrict__ off,
    int* __restrict__ bucket, int E)
{
    int base = (blockIdx.x * blockDim.x + threadIdx.x) * 8;
    if (base + 7 < E) {
        int4 d0 = *(const int4*)&dst[base];
        int4 d1 = *(const int4*)&dst[base + 4];
        int4 r0 = *(const int4*)&rank[base];
        int4 r1 = *(const int4*)&rank[base + 4];
        int4 s0 = *(const int4*)&src[base];
        int4 s1 = *(const int4*)&src[base + 4];
        bucket[off[d0.x] + r0.x] = s0.x;
        bucket[off[d0.y] + r0.y] = s0.y;
        bucket[off[d0.z] + r0.z] = s0.z;
        bucket[off[d0.w] + r0.w] = s0.w;
        bucket[off[d1.x] + r1.x] = s1.x;
        bucket[off[d1.y] + r1.y] = s1.y;
        bucket[off[d1.z] + r1.z] = s1.z;
        bucket[off[d1.w] + r1.w] = s1.w;
    } else {
        for (int e = base; e < E; ++e) bucket[off[dst[e]] + rank[e]] = src[e];
    }
}

__global__ __launch_bounds__(256) void fill_kernel(
    const int* __restrict__ src, const int* __restrict__ dst,
    int* __restrict__ cursor, int* __restrict__ bucket, int E)
{
    int e = blockIdx.x * blockDim.x + threadIdx.x;
    if (e < E) {
        int d = dst[e];
        int p = atomicAdd(&cursor[d], 1);
        bucket[p] = src[e];
    }
}

// ================================================================ fused gather + matvec
#define WPB 8  // waves per 512-thread block
#define NT  4  // nodes per wave per iteration

__device__ __forceinline__ float dot4(float4 a, float4 b)
{
    return a.x * b.x + a.y * b.y + a.z * b.z + a.w * b.w;
}

// Gather one node's agg row; group g of 16 lanes takes every 4th edge as
// float4. Returns the 4-group-reduced chunk (valid in all lanes).
__device__ __forceinline__ float4 gather_row(
    const float* __restrict__ h, const int* __restrict__ bucket,
    int beg, int end, int g, int l16, float4 init)
{
    float4 acc4 = init;
    int j = beg;
    for (; j + 8 <= end; j += 8) {
        int sa = bucket[j + g];
        int sb = bucket[j + 4 + g];
        float4 va = *(const float4*)&h[(size_t)sa * 64 + l16 * 4];
        float4 vb = *(const float4*)&h[(size_t)sb * 64 + l16 * 4];
        acc4.x += va.x + vb.x;
        acc4.y += va.y + vb.y;
        acc4.z += va.z + vb.z;
        acc4.w += va.w + vb.w;
    }
    if (j + 4 <= end) {
        int sa = bucket[j + g];
        float4 va = *(const float4*)&h[(size_t)sa * 64 + l16 * 4];
        acc4.x += va.x; acc4.y += va.y; acc4.z += va.z; acc4.w += va.w;
        j += 4;
    }
    if (j < end) {
        int jj = j + g;
        int sc = bucket[(jj < end) ? jj : (end - 1)];
        float m = (jj < end) ? 1.0f : 0.0f;
        float4 vc = *(const float4*)&h[(size_t)sc * 64 + l16 * 4];
        acc4.x = fmaf(vc.x, m, acc4.x);
        acc4.y = fmaf(vc.y, m, acc4.y);
        acc4.z = fmaf(vc.z, m, acc4.z);
        acc4.w = fmaf(vc.w, m, acc4.w);
    }
    acc4.x += __shfl_xor(acc4.x, 16, 64);
    acc4.y += __shfl_xor(acc4.y, 16, 64);
    acc4.z += __shfl_xor(acc4.z, 16, 64);
    acc4.w += __shfl_xor(acc4.w, 16, 64);
    acc4.x += __shfl_xor(acc4.x, 32, 64);
    acc4.y += __shfl_xor(acc4.y, 32, 64);
    acc4.z += __shfl_xor(acc4.z, 32, 64);
    acc4.w += __shfl_xor(acc4.w, 32, 64);
    return acc4;
}

// ---- layer kernel: out = relu((agg + (1+eps)*self) @ W^T) ----
// GATHER_L(T): literal T -> all LDS/array indexing compile-time.
#define GATHER_L(T)                                                         \
    {                                                                       \
        int i_ = i0 + (T);                                                  \
        float4 init_ = make_float4(0.f, 0.f, 0.f, 0.f);                     \
        if (g == 0) {                                                       \
            float4 sf_ = *(const float4*)&h[(size_t)i_ * 64 + l16 * 4];     \
            init_ = make_float4(s * sf_.x, s * sf_.y, s * sf_.z, s * sf_.w);\
        }                                                                   \
        int2 be_ = *(const int2*)&off[i_];                                  \
        int beg_ = __builtin_amdgcn_readfirstlane(be_.x);                   \
        int end_ = __builtin_amdgcn_readfirstlane(be_.y);                   \
        float4 red_ = gather_row(h, bucket, beg_, end_, g, l16, init_);     \
        if (g == 0) *(float4*)&rowbuf[w][T][l16 * 4] = red_;                \
    }

__global__ __launch_bounds__(512) void fused_gin_kernel(
    const float* __restrict__ h, const int* __restrict__ off,
    const int* __restrict__ bucket, const float* __restrict__ W,
    const float* __restrict__ eps, float* __restrict__ out, int n)
{
    __shared__ float Ws[64][68];           // W row-major, padded
    __shared__ float rowbuf[WPB][NT][64];  // agg rows for NT nodes
    int tid = threadIdx.x;
    for (int idx = tid; idx < 4096; idx += 512) Ws[idx >> 6][idx & 63] = W[idx];
    __syncthreads();
    float s = 1.0f + eps[0];
    int lane = tid & 63;
    int w = tid >> 6;
    int l16 = lane & 15;
    int g = lane >> 4;
    int stride = gridDim.x * WPB * NT;
    for (int i0 = (blockIdx.x * WPB + w) * NT; i0 < n; i0 += stride) {
        if (i0 + NT <= n) {  // wave-uniform hot path: straight-line x4
            GATHER_L(0)
            GATHER_L(1)
            GATHER_L(2)
            GATHER_L(3)
            __builtin_amdgcn_wave_barrier();
            const float4* wrow = (const float4*)&Ws[lane][0];
            float o0 = 0.f, o1 = 0.f, o2 = 0.f, o3 = 0.f;
#pragma unroll
            for (int k4 = 0; k4 < 16; ++k4) {
                float4 ww = wrow[k4];
                o0 += dot4(ww, *(const float4*)&rowbuf[w][0][k4 * 4]);
                o1 += dot4(ww, *(const float4*)&rowbuf[w][1][k4 * 4]);
                o2 += dot4(ww, *(const float4*)&rowbuf[w][2][k4 * 4]);
                o3 += dot4(ww, *(const float4*)&rowbuf[w][3][k4 * 4]);
            }
            out[(size_t)(i0 + 0) * 64 + lane] = fmaxf(o0, 0.f);
            out[(size_t)(i0 + 1) * 64 + lane] = fmaxf(o1, 0.f);
            out[(size_t)(i0 + 2) * 64 + lane] = fmaxf(o2, 0.f);
            out[(size_t)(i0 + 3) * 64 + lane] = fmaxf(o3, 0.f);
            __builtin_amdgcn_wave_barrier();
        } else {             // tail: one node at a time (R6 shape)
            for (int i = i0; i < n; ++i) {
                float4 init = make_float4(0.f, 0.f, 0.f, 0.f);
                if (g == 0) {
                    float4 sf = *(const float4*)&h[(size_t)i * 64 + l16 * 4];
                    init = make_float4(s * sf.x, s * sf.y, s * sf.z, s * sf.w);
                }
                int2 be = *(const int2*)&off[i];
                int beg = __builtin_amdgcn_readfirstlane(be.x);
                int end = __builtin_amdgcn_readfirstlane(be.y);
                float4 red = gather_row(h, bucket, beg, end, g, l16, init);
                if (g == 0) *(float4*)&rowbuf[w][0][l16 * 4] = red;
                __builtin_amdgcn_wave_barrier();
                const float4* wrow = (const float4*)&Ws[lane][0];
                float o = 0.f;
#pragma unroll
                for (int k4 = 0; k4 < 16; ++k4)
                    o += dot4(wrow[k4], *(const float4*)&rowbuf[w][0][k4 * 4]);
                out[(size_t)i * 64 + lane] = fmaxf(o, 0.f);
                __builtin_amdgcn_wave_barrier();
            }
        }
    }
}

// ---- final: out[i] = ( relu(agg(h1) @ W1^T) + h1[i] @ Wm^T ) / 2 ----
#define GATHER_F(T)                                                          \
    {                                                                        \
        int i_ = i0 + (T);                                                   \
        float4 init_ = make_float4(0.f, 0.f, 0.f, 0.f);                      \
        if (g == 0) {                                                        \
            float4 sf_ = *(const float4*)&h1[(size_t)i_ * 64 + l16 * 4];     \
            *(float4*)&selfbuf[w][T][l16 * 4] = sf_;                         \
            init_ = make_float4(s * sf_.x, s * sf_.y, s * sf_.z, s * sf_.w); \
        }                                                                    \
        int2 be_ = *(const int2*)&off[i_];                                   \
        int beg_ = __builtin_amdgcn_readfirstlane(be_.x);                    \
        int end_ = __builtin_amdgcn_readfirstlane(be_.y);                    \
        float4 red_ = gather_row(h1, bucket, beg_, end_, g, l16, init_);     \
        if (g == 0) *(float4*)&rowbuf[w][T][l16 * 4] = red_;                 \
    }

__global__ __launch_bounds__(512) void fused_final_csr_kernel(
    const float* __restrict__ h1, const int* __restrict__ off,
    const int* __restrict__ bucket, const float* __restrict__ W1,
    const float* __restrict__ Wm, const float* __restrict__ eps,
    float* __restrict__ out, int n)
{
    __shared__ float W1s[64][68];
    __shared__ float Wms[64][68];
    __shared__ float rowbuf[WPB][NT][64];
    __shared__ float selfbuf[WPB][NT][64];
    int tid = threadIdx.x;
    for (int idx = tid; idx < 4096; idx += 512) {
        W1s[idx >> 6][idx & 63] = W1[idx];
        Wms[idx >> 6][idx & 63] = Wm[idx];
    }
    __syncthreads();
    float s = 1.0f + eps[0];
    int lane = tid & 63;
    int w = tid >> 6;
    int l16 = lane & 15;
    int g = lane >> 4;
    int stride = gridDim.x * WPB * NT;
    for (int i0 = (blockIdx.x * WPB + w) * NT; i0 < n; i0 += stride) {
        if (i0 + NT <= n) {
            GATHER_F(0)
            GATHER_F(1)
            GATHER_F(2)
            GATHER_F(3)
            __builtin_amdgcn_wave_barrier();
            const float4* w1row = (const float4*)&W1s[lane][0];
            const float4* wmrow = (const float4*)&Wms[lane][0];
            float a0 = 0.f, a1 = 0.f, a2 = 0.f, a3 = 0.f;  // agg @ W1^T
            float b0 = 0.f, b1 = 0.f, b2 = 0.f, b3 = 0.f;  // self @ Wm^T
#pragma unroll
            for (int k4 = 0; k4 < 16; ++k4) {
                float4 w1v = w1row[k4];
                float4 wmv = wmrow[k4];
                a0 += dot4(w1v, *(const float4*)&rowbuf[w][0][k4 * 4]);
                a1 += dot4(w1v, *(const float4*)&rowbuf[w][1][k4 * 4]);
                a2 += dot4(w1v, *(const float4*)&rowbuf[w][2][k4 * 4]);
                a3 += dot4(w1v, *(const float4*)&rowbuf[w][3][k4 * 4]);
                b0 += dot4(wmv, *(const float4*)&selfbuf[w][0][k4 * 4]);
                b1 += dot4(wmv, *(const float4*)&selfbuf[w][1][k4 * 4]);
                b2 += dot4(wmv, *(const float4*)&selfbuf[w][2][k4 * 4]);
                b3 += dot4(wmv, *(const float4*)&selfbuf[w][3][k4 * 4]);
            }
            out[(size_t)(i0 + 0) * 64 + lane] = (fmaxf(a0, 0.f) + b0) * 0.5f;
            out[(size_t)(i0 + 1) * 64 + lane] = (fmaxf(a1, 0.f) + b1) * 0.5f;
            out[(size_t)(i0 + 2) * 64 + lane] = (fmaxf(a2, 0.f) + b2) * 0.5f;
            out[(size_t)(i0 + 3) * 64 + lane] = (fmaxf(a3, 0.f) + b3) * 0.5f;
            __builtin_amdgcn_wave_barrier();
        } else {
            for (int i = i0; i < n; ++i) {
                float4 init = make_float4(0.f, 0.f, 0.f, 0.f);
                if (g == 0) {
                    float4 sf = *(const float4*)&h1[(size_t)i * 64 + l16 * 4];
                    *(float4*)&selfbuf[w][0][l16 * 4] = sf;
                    init = make_float4(s * sf.x, s * sf.y, s * sf.z, s * sf.w);
                }
                int2 be = *(const int2*)&off[i];
                int beg = __builtin_amdgcn_readfirstlane(be.x);
                int end = __builtin_amdgcn_readfirstlane(be.y);
                float4 red = gather_row(h1, bucket, beg, end, g, l16, init);
                if (g == 0) *(float4*)&rowbuf[w][0][l16 * 4] = red;
                __builtin_amdgcn_wave_barrier();
                const float4* w1row = (const float4*)&W1s[lane][0];
                const float4* wmrow = (const float4*)&Wms[lane][0];
                float oa = 0.f, ob = 0.f;
#pragma unroll
                for (int k4 = 0; k4 < 16; ++k4) {
                    oa += dot4(w1row[k4], *(const float4*)&rowbuf[w][0][k4 * 4]);
                    ob += dot4(wmrow[k4], *(const float4*)&selfbuf[w][0][k4 * 4]);
                }
                out[(size_t)i * 64 + lane] = (fmaxf(oa, 0.f) + ob) * 0.5f;
                __builtin_amdgcn_wave_barrier();
            }
        }
    }
}

// ================================================================ R1 fallback (atomic scatter)
__global__ __launch_bounds__(256) void init_scale_kernel(
    const float* __restrict__ h, const float* __restrict__ eps,
    float* __restrict__ agg, int total4)
{
    float s = 1.0f + eps[0];
    int i = blockIdx.x * blockDim.x + threadIdx.x;
    int stride = gridDim.x * blockDim.x;
    const float4* h4 = (const float4*)h;
    float4* a4 = (float4*)agg;
    for (; i < total4; i += stride) {
        float4 v = h4[i];
        v.x *= s; v.y *= s; v.z *= s; v.w *= s;
        a4[i] = v;
    }
}

__global__ __launch_bounds__(256) void scatter_kernel(
    const float* __restrict__ h, const int* __restrict__ src,
    const int* __restrict__ dst, float* __restrict__ agg, int E)
{
    int lane = threadIdx.x & 63;
    int e = blockIdx.x * 4 + (threadIdx.x >> 6);
    if (e >= E) return;
    int s = src[e];
    int d = dst[e];
    atomicAdd(&agg[(size_t)d * 64 + lane], h[(size_t)s * 64 + lane]);
}

__global__ __launch_bounds__(256) void gemm_relu_kernel(
    const float* __restrict__ A, const float* __restrict__ W,
    float* __restrict__ out, int n)
{
    __shared__ float Wt[64][65];
    __shared__ float rowbuf[4][64];
    int tid = threadIdx.x;
    for (int i = tid; i < 4096; i += 256) Wt[i & 63][i >> 6] = W[i];
    __syncthreads();
    int lane = tid & 63;
    int w = tid >> 6;
    int wavesTotal = gridDim.x * 4;
    for (int i = blockIdx.x * 4 + w; i < n; i += wavesTotal) {
        rowbuf[w][lane] = A[(size_t)i * 64 + lane];
        __builtin_amdgcn_wave_barrier();
        float o = 0.f;
#pragma unroll
        for (int k = 0; k < 64; ++k) o += rowbuf[w][k] * Wt[k][lane];
        out[(size_t)i * 64 + lane] = fmaxf(o, 0.f);
        __builtin_amdgcn_wave_barrier();
    }
}

__global__ __launch_bounds__(256) void final_kernel(
    const float* __restrict__ Agg, const float* __restrict__ H1,
    const float* __restrict__ W1, const float* __restrict__ Wm,
    float* __restrict__ out, int n)
{
    __shared__ float W1t[64][65];
    __shared__ float Wmt[64][65];
    __shared__ float rowbuf[4][64];
    __shared__ float selfbuf[4][64];
    int tid = threadIdx.x;
    for (int i = tid; i < 4096; i += 256) {
        W1t[i & 63][i >> 6] = W1[i];
        Wmt[i & 63][i >> 6] = Wm[i];
    }
    __syncthreads();
    int lane = tid & 63;
    int w = tid >> 6;
    int wavesTotal = gridDim.x * 4;
    for (int i = blockIdx.x * 4 + w; i < n; i += wavesTotal) {
        rowbuf[w][lane] = Agg[(size_t)i * 64 + lane];
        selfbuf[w][lane] = H1[(size_t)i * 64 + lane];
        __builtin_amdgcn_wave_barrier();
        float o1 = 0.f, o2 = 0.f;
#pragma unroll
        for (int k = 0; k < 64; ++k) {
            o1 += rowbuf[w][k] * W1t[k][lane];
            o2 += selfbuf[w][k] * Wmt[k][lane];
        }
        out[(size_t)i * 64 + lane] = (fmaxf(o1, 0.f) + o2) * 0.5f;
        __builtin_amdgcn_wave_barrier();
    }
}

// ================================================================ launch
extern "C" void kernel_launch(void* const* d_in, const int* in_sizes, int n_in,
                              void* d_out, int out_size, void* d_ws, size_t ws_size,
                              hipStream_t stream)
{
    const float* x    = (const float*)d_in[0];
    const int*   ei   = (const int*)d_in[1];
    const float* W0   = (const float*)d_in[2];
    const float* eps0 = (const float*)d_in[3];
    const float* W1   = (const float*)d_in[4];
    const float* eps1 = (const float*)d_in[5];
    const float* Wm   = (const float*)d_in[6];
    float* out = (float*)d_out;

    int n = in_sizes[0] / 64;   // 100000
    int E = in_sizes[1] / 2;    // 1600000
    const int* src = ei;
    const int* dst = ei + E;

    auto align1k = [](size_t v) { return (v + 1023) & ~(size_t)1023; };
    size_t h1_off     = 0;
    size_t off_off    = align1k(h1_off + (size_t)n * 64 * 4);
    size_t deg_off    = align1k(off_off + (size_t)(n + 1) * 4);
    size_t cursor_off = align1k(deg_off + (size_t)n * 4);
    size_t bsum_off   = align1k(cursor_off + (size_t)n * 4);
    size_t bucket_off = align1k(bsum_off + 256 * 4);
    size_t rank_off   = align1k(bucket_off + (size_t)E * 4);
    size_t need_B     = rank_off;                  // ~33.2 MB
    size_t need_A     = rank_off + (size_t)E * 4;  // ~39.6 MB

    int nb = (n + 1023) / 1024;
    int e4Blocks  = (E + 1023) / 1024;
    int e8Blocks  = (E + 2047) / 2048;
    int e16Blocks = (E + 4095) / 4096;

    if (ws_size >= need_B) {
        float* h1    = (float*)((char*)d_ws + h1_off);
        int* off     = (int*)((char*)d_ws + off_off);
        int* deg     = (int*)((char*)d_ws + deg_off);
        int* cursor  = (int*)((char*)d_ws + cursor_off);
        int* bsum    = (int*)((char*)d_ws + bsum_off);
        int* bucket  = (int*)((char*)d_ws + bucket_off);
        int* rank    = (int*)((char*)d_ws + rank_off);

        zero_int_kernel<<<256, 256, 0, stream>>>(deg, n);
        if (ws_size >= need_A) {
            hist_rank_kernel<<<e16Blocks, 256, 0, stream>>>(dst, deg, rank, E);
            scanA_kernel<<<nb, 256, 0, stream>>>(deg, off, bsum, n);
            scanB_kernel<<<1, 256, 0, stream>>>(bsum, nb);
            scanC_kernel<<<nb, 256, 0, stream>>>(off, (int*)nullptr, bsum, n, E);
            fill_rank_kernel<<<e8Blocks, 256, 0, stream>>>(src, dst, rank, off, bucket, E);
        } else {
            hist_kernel<<<e4Blocks, 256, 0, stream>>>(dst, deg, E);
            scanA_kernel<<<nb, 256, 0, stream>>>(deg, off, bsum, n);
            scanB_kernel<<<1, 256, 0, stream>>>(bsum, nb);
            scanC_kernel<<<nb, 256, 0, stream>>>(off, cursor, bsum, n, E);
            fill_kernel<<<(E + 255) / 256, 256, 0, stream>>>(src, dst, cursor, bucket, E);
        }

        // gin: ~25.4KB LDS -> 4 blocks/CU (32 waves); grid 1024
        fused_gin_kernel<<<1024, 512, 0, stream>>>(x, off, bucket, W0, eps0, h1, n);
        // final: ~50.3KB LDS -> 3 blocks/CU; grid 768
        fused_final_csr_kernel<<<768, 512, 0, stream>>>(h1, off, bucket, W1, Wm, eps1, out, n);
    } else {
        float* agg = (float*)d_ws;
        float* h1  = out;
        int total4 = n * 16;
        int scatterBlocks = (E + 3) / 4;

        init_scale_kernel<<<2048, 256, 0, stream>>>(x, eps0, agg, total4);
        scatter_kernel<<<scatterBlocks, 256, 0, stream>>>(x, src, dst, agg, E);
        gemm_relu_kernel<<<2048, 256, 0, stream>>>(agg, W0, h1, n);
        init_scale_kernel<<<2048, 256, 0, stream>>>(h1, eps1, agg, total4);
        scatter_kernel<<<scatterBlocks, 256, 0, stream>>>(h1, src, dst, agg, E);
        final_kernel<<<2048, 256, 0, stream>>>(agg, h1, W1, Wm, out, n);
    }
}

// Round 9
// 241.801 us; speedup vs baseline: 3.9259x; 1.2900x over previous
//
#include <hip/hip_runtime.h>
#include <hip/hip_fp16.h>

// GIN: h1 = relu((scatter_add(x) + (1+eps0)*x) @ W0^T)
//      h2 = relu((scatter_add(h1) + (1+eps1)*h1) @ W1^T)
//      out = (h1 @ Wm^T + h2) / 2
//
// R9: revert fused kernels to the R6 structure (NT=4 refuted: 120 vs 87us,
// occupancy 54->33%), and attack the measured constraint: gather BYTE volume
// (FETCH 187MB/pass, L3 absorbs only ~55% of the 410MB random-row reads).
// Tier A2: fp16 mirrors of x and h1 (12.8MB each) -> gather loads are 8B
// uint2, accumulated with packed v_pk_add_f16 (VALU/edge DROPS), converted
// to fp32 once per node for the (unchanged) fp32 matvec. h1 exists ONLY in
// fp16 (self + Wm paths read it too; err << 0.6 threshold). ws ~39.3MB
// (< 39.6MB proven). Fallbacks: tier B fp32-CSR (33.2MB), tier C scatter.

// ================================================================ CSR build
__global__ __launch_bounds__(256) void zero_int_kernel(int* __restrict__ p, int n)
{
    int i = blockIdx.x * blockDim.x + threadIdx.x;
    int stride = gridDim.x * blockDim.x;
    for (; i < n; i += stride) p[i] = 0;
}

__global__ __launch_bounds__(256) void hist_rank_kernel(
    const int* __restrict__ dst, int* __restrict__ deg,
    int* __restrict__ rank, int E)
{
    int base = (blockIdx.x * blockDim.x + threadIdx.x) * 16;
    if (base + 15 < E) {
        int4 a = *(const int4*)&dst[base];
        int4 b = *(const int4*)&dst[base + 4];
        int4 c = *(const int4*)&dst[base + 8];
        int4 d = *(const int4*)&dst[base + 12];
        int r0 = atomicAdd(&deg[a.x], 1);
        int r1 = atomicAdd(&deg[a.y], 1);
        int r2 = atomicAdd(&deg[a.z], 1);
        int r3 = atomicAdd(&deg[a.w], 1);
        int r4 = atomicAdd(&deg[b.x], 1);
        int r5 = atomicAdd(&deg[b.y], 1);
        int r6 = atomicAdd(&deg[b.z], 1);
        int r7 = atomicAdd(&deg[b.w], 1);
        int r8 = atomicAdd(&deg[c.x], 1);
        int r9 = atomicAdd(&deg[c.y], 1);
        int rA = atomicAdd(&deg[c.z], 1);
        int rB = atomicAdd(&deg[c.w], 1);
        int rC = atomicAdd(&deg[d.x], 1);
        int rD = atomicAdd(&deg[d.y], 1);
        int rE = atomicAdd(&deg[d.z], 1);
        int rF = atomicAdd(&deg[d.w], 1);
        *(int4*)&rank[base]      = make_int4(r0, r1, r2, r3);
        *(int4*)&rank[base + 4]  = make_int4(r4, r5, r6, r7);
        *(int4*)&rank[base + 8]  = make_int4(r8, r9, rA, rB);
        *(int4*)&rank[base + 12] = make_int4(rC, rD, rE, rF);
    } else {
        for (int e = base; e < E; ++e) rank[e] = atomicAdd(&deg[dst[e]], 1);
    }
}

__global__ __launch_bounds__(256) void hist_kernel(
    const int* __restrict__ dst, int* __restrict__ deg, int E)
{
    int e4 = (blockIdx.x * blockDim.x + threadIdx.x) * 4;
    if (e4 + 3 < E) {
        int4 d = *(const int4*)&dst[e4];
        atomicAdd(&deg[d.x], 1);
        atomicAdd(&deg[d.y], 1);
        atomicAdd(&deg[d.z], 1);
        atomicAdd(&deg[d.w], 1);
    } else {
        for (int e = e4; e < E; ++e) atomicAdd(&deg[dst[e]], 1);
    }
}

__global__ __launch_bounds__(256) void scanA_kernel(
    const int* __restrict__ deg, int* __restrict__ off,
    int* __restrict__ bsum, int n)
{
    __shared__ int tmp[256];
    int t = threadIdx.x;
    int base = blockIdx.x * 1024 + t * 4;
    int v0 = 0, v1 = 0, v2 = 0, v3 = 0;
    if (base + 3 < n) {
        int4 q = *(const int4*)&deg[base];
        v0 = q.x; v1 = q.y; v2 = q.z; v3 = q.w;
    } else {
        if (base + 0 < n) v0 = deg[base + 0];
        if (base + 1 < n) v1 = deg[base + 1];
        if (base + 2 < n) v2 = deg[base + 2];
    }
    int tot = v0 + v1 + v2 + v3;
    tmp[t] = tot;
    __syncthreads();
    for (int d = 1; d < 256; d <<= 1) {
        int x = (t >= d) ? tmp[t - d] : 0;
        __syncthreads();
        tmp[t] += x;
        __syncthreads();
    }
    int incl = tmp[t];
    int p = incl - tot;
    if (base + 0 < n) off[base + 0] = p;
    if (base + 1 < n) off[base + 1] = p + v0;
    if (base + 2 < n) off[base + 2] = p + v0 + v1;
    if (base + 3 < n) off[base + 3] = p + v0 + v1 + v2;
    if (t == 255) bsum[blockIdx.x] = incl;
}

__global__ __launch_bounds__(256) void scanB_kernel(int* __restrict__ bsum, int nb)
{
    __shared__ int tmp[256];
    int t = threadIdx.x;
    int v = (t < nb) ? bsum[t] : 0;
    tmp[t] = v;
    __syncthreads();
    for (int d = 1; d < 256; d <<= 1) {
        int x = (t >= d) ? tmp[t - d] : 0;
        __syncthreads();
        tmp[t] += x;
        __syncthreads();
    }
    if (t < nb) bsum[t] = tmp[t] - v;
}

__global__ __launch_bounds__(256) void scanC_kernel(
    int* __restrict__ off, int* __restrict__ cursor,
    const int* __restrict__ bsum, int n, int E)
{
    int t = threadIdx.x;
    int add = bsum[blockIdx.x];
    int base = blockIdx.x * 1024 + t * 4;
#pragma unroll
    for (int q = 0; q < 4; ++q) {
        int idx = base + q;
        if (idx < n) {
            int v = off[idx] + add;
            off[idx] = v;
            if (cursor) cursor[idx] = v;
        }
    }
    if (blockIdx.x == 0 && t == 0) off[n] = E;
}

__global__ __launch_bounds__(256) void fill_rank_kernel(
    const int* __restrict__ src, const int* __restrict__ dst,
    const int* __restrict__ rank, const int* __restrict__ off,
    int* __restrict__ bucket, int E)
{
    int base = (blockIdx.x * blockDim.x + threadIdx.x) * 8;
    if (base + 7 < E) {
        int4 d0 = *(const int4*)&dst[base];
        int4 d1 = *(const int4*)&dst[base + 4];
        int4 r0 = *(const int4*)&rank[base];
        int4 r1 = *(const int4*)&rank[base + 4];
        int4 s0 = *(const int4*)&src[base];
        int4 s1 = *(const int4*)&src[base + 4];
        bucket[off[d0.x] + r0.x] = s0.x;
        bucket[off[d0.y] + r0.y] = s0.y;
        bucket[off[d0.z] + r0.z] = s0.z;
        bucket[off[d0.w] + r0.w] = s0.w;
        bucket[off[d1.x] + r1.x] = s1.x;
        bucket[off[d1.y] + r1.y] = s1.y;
        bucket[off[d1.z] + r1.z] = s1.z;
        bucket[off[d1.w] + r1.w] = s1.w;
    } else {
        for (int e = base; e < E; ++e) bucket[off[dst[e]] + rank[e]] = src[e];
    }
}

__global__ __launch_bounds__(256) void fill_kernel(
    const int* __restrict__ src, const int* __restrict__ dst,
    int* __restrict__ cursor, int* __restrict__ bucket, int E)
{
    int e = blockIdx.x * blockDim.x + threadIdx.x;
    if (e < E) {
        int d = dst[e];
        int p = atomicAdd(&cursor[d], 1);
        bucket[p] = src[e];
    }
}

// ================================================================ fp32 -> fp16 convert
__global__ __launch_bounds__(256) void f32_to_f16_kernel(
    const float* __restrict__ in, __half* __restrict__ out, int total4)
{
    int i = blockIdx.x * blockDim.x + threadIdx.x;
    int stride = gridDim.x * blockDim.x;
    const float4* in4 = (const float4*)in;
    uint2* out4 = (uint2*)out;
    for (; i < total4; i += stride) {
        float4 v = in4[i];
        __half2 a = __floats2half2_rn(v.x, v.y);
        __half2 b = __floats2half2_rn(v.z, v.w);
        uint2 u;
        u.x = __builtin_bit_cast(unsigned int, a);
        u.y = __builtin_bit_cast(unsigned int, b);
        out4[i] = u;
    }
}

// ================================================================ fp16-gather fused kernels
#define WPB 8  // waves per 512-thread block

__device__ __forceinline__ float dot4(float4 a, float4 b)
{
    return a.x * b.x + a.y * b.y + a.z * b.z + a.w * b.w;
}

__device__ __forceinline__ __half2 bc_h2(unsigned int u)
{
    return __builtin_bit_cast(__half2, u);
}

// gin layer: outh[i] = fp16( relu((agg + (1+eps)*self) @ W^T) ), gather from hh (fp16)
__global__ __launch_bounds__(512) void fused_gin_h_kernel(
    const __half* __restrict__ hh, const int* __restrict__ off,
    const int* __restrict__ bucket, const float* __restrict__ W,
    const float* __restrict__ eps, __half* __restrict__ outh, int n)
{
    __shared__ float Ws[64][68];      // W row-major, padded
    __shared__ float P[WPB][4][64];   // per-group partial rows
    __shared__ float rowbuf[WPB][64];
    int tid = threadIdx.x;
    for (int idx = tid; idx < 4096; idx += 512) Ws[idx >> 6][idx & 63] = W[idx];
    __syncthreads();
    float s = 1.0f + eps[0];
    int lane = tid & 63;
    int w = tid >> 6;
    int l16 = lane & 15;
    int g = lane >> 4;
    int wavesTotal = gridDim.x * WPB;
    for (int i = blockIdx.x * WPB + w; i < n; i += wavesTotal) {
        int2 be = *(const int2*)&off[i];
        int beg = __builtin_amdgcn_readfirstlane(be.x);
        int end = __builtin_amdgcn_readfirstlane(be.y);
        __half2 ha = bc_h2(0u), hb = bc_h2(0u);   // packed fp16 accumulators
        float4 acc4 = make_float4(0.f, 0.f, 0.f, 0.f);
        int j = beg;
        for (; j + 8 <= end; j += 8) {
            int sa = bucket[j + g];
            int sb = bucket[j + 4 + g];
            uint2 va = *(const uint2*)&hh[(size_t)sa * 64 + l16 * 4];
            uint2 vb = *(const uint2*)&hh[(size_t)sb * 64 + l16 * 4];
            ha = __hadd2(__hadd2(ha, bc_h2(va.x)), bc_h2(vb.x));
            hb = __hadd2(__hadd2(hb, bc_h2(va.y)), bc_h2(vb.y));
        }
        if (j + 4 <= end) {
            int sa = bucket[j + g];
            uint2 va = *(const uint2*)&hh[(size_t)sa * 64 + l16 * 4];
            ha = __hadd2(ha, bc_h2(va.x));
            hb = __hadd2(hb, bc_h2(va.y));
            j += 4;
        }
        if (j < end) {  // 1..3 tail edges: fp32 masked
            int jj = j + g;
            int sc = bucket[(jj < end) ? jj : (end - 1)];
            float m = (jj < end) ? 1.0f : 0.0f;
            uint2 vc = *(const uint2*)&hh[(size_t)sc * 64 + l16 * 4];
            float2 c01 = __half22float2(bc_h2(vc.x));
            float2 c23 = __half22float2(bc_h2(vc.y));
            acc4.x = fmaf(c01.x, m, acc4.x);
            acc4.y = fmaf(c01.y, m, acc4.y);
            acc4.z = fmaf(c23.x, m, acc4.z);
            acc4.w = fmaf(c23.y, m, acc4.w);
        }
        float2 f01 = __half22float2(ha);
        float2 f23 = __half22float2(hb);
        acc4.x += f01.x; acc4.y += f01.y; acc4.z += f23.x; acc4.w += f23.y;
        if (g == 0) {   // self term
            uint2 sv = *(const uint2*)&hh[(size_t)i * 64 + l16 * 4];
            float2 s01 = __half22float2(bc_h2(sv.x));
            float2 s23 = __half22float2(bc_h2(sv.y));
            acc4.x = fmaf(s01.x, s, acc4.x);
            acc4.y = fmaf(s01.y, s, acc4.y);
            acc4.z = fmaf(s23.x, s, acc4.z);
            acc4.w = fmaf(s23.y, s, acc4.w);
        }
        *(float4*)&P[w][g][l16 * 4] = acc4;
        __builtin_amdgcn_wave_barrier();
        float r0 = P[w][0][lane], r1 = P[w][1][lane];
        float r2 = P[w][2][lane], r3 = P[w][3][lane];
        rowbuf[w][lane] = (r0 + r1) + (r2 + r3);
        __builtin_amdgcn_wave_barrier();
        const float4* wrow = (const float4*)&Ws[lane][0];
        const float4* rrow = (const float4*)&rowbuf[w][0];
        float o = 0.f;
#pragma unroll
        for (int k4 = 0; k4 < 16; ++k4) o += dot4(wrow[k4], rrow[k4]);
        outh[(size_t)i * 64 + lane] = __float2half(fmaxf(o, 0.f));
        __builtin_amdgcn_wave_barrier();
    }
}

// final: out[i] = ( relu(agg(h1) @ W1^T) + h1[i] @ Wm^T ) / 2, h1 in fp16
__global__ __launch_bounds__(512) void fused_final_h_kernel(
    const __half* __restrict__ hh1, const int* __restrict__ off,
    const int* __restrict__ bucket, const float* __restrict__ W1,
    const float* __restrict__ Wm, const float* __restrict__ eps,
    float* __restrict__ out, int n)
{
    __shared__ float W1s[64][68];
    __shared__ float Wms[64][68];
    __shared__ float P[WPB][4][64];
    __shared__ float rowbuf[WPB][64];
    __shared__ float selfbuf[WPB][64];
    int tid = threadIdx.x;
    for (int idx = tid; idx < 4096; idx += 512) {
        W1s[idx >> 6][idx & 63] = W1[idx];
        Wms[idx >> 6][idx & 63] = Wm[idx];
    }
    __syncthreads();
    float s = 1.0f + eps[0];
    int lane = tid & 63;
    int w = tid >> 6;
    int l16 = lane & 15;
    int g = lane >> 4;
    int wavesTotal = gridDim.x * WPB;
    for (int i = blockIdx.x * WPB + w; i < n; i += wavesTotal) {
        int2 be = *(const int2*)&off[i];
        int beg = __builtin_amdgcn_readfirstlane(be.x);
        int end = __builtin_amdgcn_readfirstlane(be.y);
        __half2 ha = bc_h2(0u), hb = bc_h2(0u);
        float4 acc4 = make_float4(0.f, 0.f, 0.f, 0.f);
        int j = beg;
        for (; j + 8 <= end; j += 8) {
            int sa = bucket[j + g];
            int sb = bucket[j + 4 + g];
            uint2 va = *(const uint2*)&hh1[(size_t)sa * 64 + l16 * 4];
            uint2 vb = *(const uint2*)&hh1[(size_t)sb * 64 + l16 * 4];
            ha = __hadd2(__hadd2(ha, bc_h2(va.x)), bc_h2(vb.x));
            hb = __hadd2(__hadd2(hb, bc_h2(va.y)), bc_h2(vb.y));
        }
        if (j + 4 <= end) {
            int sa = bucket[j + g];
            uint2 va = *(const uint2*)&hh1[(size_t)sa * 64 + l16 * 4];
            ha = __hadd2(ha, bc_h2(va.x));
            hb = __hadd2(hb, bc_h2(va.y));
            j += 4;
        }
        if (j < end) {
            int jj = j + g;
            int sc = bucket[(jj < end) ? jj : (end - 1)];
            float m = (jj < end) ? 1.0f : 0.0f;
            uint2 vc = *(const uint2*)&hh1[(size_t)sc * 64 + l16 * 4];
            float2 c01 = __half22float2(bc_h2(vc.x));
            float2 c23 = __half22float2(bc_h2(vc.y));
            acc4.x = fmaf(c01.x, m, acc4.x);
            acc4.y = fmaf(c01.y, m, acc4.y);
            acc4.z = fmaf(c23.x, m, acc4.z);
            acc4.w = fmaf(c23.y, m, acc4.w);
        }
        float2 f01 = __half22float2(ha);
        float2 f23 = __half22float2(hb);
        acc4.x += f01.x; acc4.y += f01.y; acc4.z += f23.x; acc4.w += f23.y;
        if (g == 0) {   // self: stash fp32 copy + add (1+eps)*self
            uint2 sv = *(const uint2*)&hh1[(size_t)i * 64 + l16 * 4];
            float2 s01 = __half22float2(bc_h2(sv.x));
            float2 s23 = __half22float2(bc_h2(sv.y));
            float4 sf = make_float4(s01.x, s01.y, s23.x, s23.y);
            *(float4*)&selfbuf[w][l16 * 4] = sf;
            acc4.x = fmaf(sf.x, s, acc4.x);
            acc4.y = fmaf(sf.y, s, acc4.y);
            acc4.z = fmaf(sf.z, s, acc4.z);
            acc4.w = fmaf(sf.w, s, acc4.w);
        }
        *(float4*)&P[w][g][l16 * 4] = acc4;
        __builtin_amdgcn_wave_barrier();
        float r0 = P[w][0][lane], r1 = P[w][1][lane];
        float r2 = P[w][2][lane], r3 = P[w][3][lane];
        rowbuf[w][lane] = (r0 + r1) + (r2 + r3);
        __builtin_amdgcn_wave_barrier();
        const float4* w1row = (const float4*)&W1s[lane][0];
        const float4* wmrow = (const float4*)&Wms[lane][0];
        const float4* rrow  = (const float4*)&rowbuf[w][0];
        const float4* srow  = (const float4*)&selfbuf[w][0];
        float o1 = 0.f, o2 = 0.f;
#pragma unroll
        for (int k4 = 0; k4 < 16; ++k4) {
            o1 += dot4(w1row[k4], rrow[k4]);
            o2 += dot4(wmrow[k4], srow[k4]);
        }
        out[(size_t)i * 64 + lane] = (fmaxf(o1, 0.f) + o2) * 0.5f;
        __builtin_amdgcn_wave_barrier();
    }
}

// ================================================================ tier B: fp32 fused (R6-proven)
__device__ __forceinline__ float4 gather_row_f32(
    const float* __restrict__ h, const int* __restrict__ bucket,
    int beg, int end, int g, int l16, float4 acc4)
{
    int j = beg;
    for (; j + 8 <= end; j += 8) {
        int sa = bucket[j + g];
        int sb = bucket[j + 4 + g];
        float4 va = *(const float4*)&h[(size_t)sa * 64 + l16 * 4];
        float4 vb = *(const float4*)&h[(size_t)sb * 64 + l16 * 4];
        acc4.x += va.x + vb.x;
        acc4.y += va.y + vb.y;
        acc4.z += va.z + vb.z;
        acc4.w += va.w + vb.w;
    }
    if (j + 4 <= end) {
        int sa = bucket[j + g];
        float4 va = *(const float4*)&h[(size_t)sa * 64 + l16 * 4];
        acc4.x += va.x; acc4.y += va.y; acc4.z += va.z; acc4.w += va.w;
        j += 4;
    }
    if (j < end) {
        int jj = j + g;
        int sc = bucket[(jj < end) ? jj : (end - 1)];
        float m = (jj < end) ? 1.0f : 0.0f;
        float4 vc = *(const float4*)&h[(size_t)sc * 64 + l16 * 4];
        acc4.x = fmaf(vc.x, m, acc4.x);
        acc4.y = fmaf(vc.y, m, acc4.y);
        acc4.z = fmaf(vc.z, m, acc4.z);
        acc4.w = fmaf(vc.w, m, acc4.w);
    }
    return acc4;
}

__global__ __launch_bounds__(512) void fused_gin_kernel(
    const float* __restrict__ h, const int* __restrict__ off,
    const int* __restrict__ bucket, const float* __restrict__ W,
    const float* __restrict__ eps, float* __restrict__ out, int n)
{
    __shared__ float Ws[64][68];
    __shared__ float P[WPB][4][64];
    __shared__ float rowbuf[WPB][64];
    int tid = threadIdx.x;
    for (int idx = tid; idx < 4096; idx += 512) Ws[idx >> 6][idx & 63] = W[idx];
    __syncthreads();
    float s = 1.0f + eps[0];
    int lane = tid & 63;
    int w = tid >> 6;
    int l16 = lane & 15;
    int g = lane >> 4;
    int wavesTotal = gridDim.x * WPB;
    for (int i = blockIdx.x * WPB + w; i < n; i += wavesTotal) {
        float4 init = make_float4(0.f, 0.f, 0.f, 0.f);
        if (g == 0) {
            float4 self4 = *(const float4*)&h[(size_t)i * 64 + l16 * 4];
            init = make_float4(s * self4.x, s * self4.y, s * self4.z, s * self4.w);
        }
        int2 be = *(const int2*)&off[i];
        int beg = __builtin_amdgcn_readfirstlane(be.x);
        int end = __builtin_amdgcn_readfirstlane(be.y);
        float4 acc4 = gather_row_f32(h, bucket, beg, end, g, l16, init);
        *(float4*)&P[w][g][l16 * 4] = acc4;
        __builtin_amdgcn_wave_barrier();
        float r0 = P[w][0][lane], r1 = P[w][1][lane];
        float r2 = P[w][2][lane], r3 = P[w][3][lane];
        rowbuf[w][lane] = (r0 + r1) + (r2 + r3);
        __builtin_amdgcn_wave_barrier();
        const float4* wrow = (const float4*)&Ws[lane][0];
        const float4* rrow = (const float4*)&rowbuf[w][0];
        float o = 0.f;
#pragma unroll
        for (int k4 = 0; k4 < 16; ++k4) o += dot4(wrow[k4], rrow[k4]);
        out[(size_t)i * 64 + lane] = fmaxf(o, 0.f);
        __builtin_amdgcn_wave_barrier();
    }
}

__global__ __launch_bounds__(512) void fused_final_csr_kernel(
    const float* __restrict__ h1, const int* __restrict__ off,
    const int* __restrict__ bucket, const float* __restrict__ W1,
    const float* __restrict__ Wm, const float* __restrict__ eps,
    float* __restrict__ out, int n)
{
    __shared__ float W1s[64][68];
    __shared__ float Wms[64][68];
    __shared__ float P[WPB][4][64];
    __shared__ float rowbuf[WPB][64];
    __shared__ float selfbuf[WPB][64];
    int tid = threadIdx.x;
    for (int idx = tid; idx < 4096; idx += 512) {
        W1s[idx >> 6][idx & 63] = W1[idx];
        Wms[idx >> 6][idx & 63] = Wm[idx];
    }
    __syncthreads();
    float s = 1.0f + eps[0];
    int lane = tid & 63;
    int w = tid >> 6;
    int l16 = lane & 15;
    int g = lane >> 4;
    int wavesTotal = gridDim.x * WPB;
    for (int i = blockIdx.x * WPB + w; i < n; i += wavesTotal) {
        float4 init = make_float4(0.f, 0.f, 0.f, 0.f);
        if (g == 0) {
            float4 self4 = *(const float4*)&h1[(size_t)i * 64 + l16 * 4];
            *(float4*)&selfbuf[w][l16 * 4] = self4;
            init = make_float4(s * self4.x, s * self4.y, s * self4.z, s * self4.w);
        }
        int2 be = *(const int2*)&off[i];
        int beg = __builtin_amdgcn_readfirstlane(be.x);
        int end = __builtin_amdgcn_readfirstlane(be.y);
        float4 acc4 = gather_row_f32(h1, bucket, beg, end, g, l16, init);
        *(float4*)&P[w][g][l16 * 4] = acc4;
        __builtin_amdgcn_wave_barrier();
        float r0 = P[w][0][lane], r1 = P[w][1][lane];
        float r2 = P[w][2][lane], r3 = P[w][3][lane];
        rowbuf[w][lane] = (r0 + r1) + (r2 + r3);
        __builtin_amdgcn_wave_barrier();
        const float4* w1row = (const float4*)&W1s[lane][0];
        const float4* wmrow = (const float4*)&Wms[lane][0];
        const float4* rrow  = (const float4*)&rowbuf[w][0];
        const float4* srow  = (const float4*)&selfbuf[w][0];
        float o1 = 0.f, o2 = 0.f;
#pragma unroll
        for (int k4 = 0; k4 < 16; ++k4) {
            o1 += dot4(w1row[k4], rrow[k4]);
            o2 += dot4(wmrow[k4], srow[k4]);
        }
        out[(size_t)i * 64 + lane] = (fmaxf(o1, 0.f) + o2) * 0.5f;
        __builtin_amdgcn_wave_barrier();
    }
}

// ================================================================ tier C: atomic scatter
__global__ __launch_bounds__(256) void init_scale_kernel(
    const float* __restrict__ h, const float* __restrict__ eps,
    float* __restrict__ agg, int total4)
{
    float s = 1.0f + eps[0];
    int i = blockIdx.x * blockDim.x + threadIdx.x;
    int stride = gridDim.x * blockDim.x;
    const float4* h4 = (const float4*)h;
    float4* a4 = (float4*)agg;
    for (; i < total4; i += stride) {
        float4 v = h4[i];
        v.x *= s; v.y *= s; v.z *= s; v.w *= s;
        a4[i] = v;
    }
}

__global__ __launch_bounds__(256) void scatter_kernel(
    const float* __restrict__ h, const int* __restrict__ src,
    const int* __restrict__ dst, float* __restrict__ agg, int E)
{
    int lane = threadIdx.x & 63;
    int e = blockIdx.x * 4 + (threadIdx.x >> 6);
    if (e >= E) return;
    int s = src[e];
    int d = dst[e];
    atomicAdd(&agg[(size_t)d * 64 + lane], h[(size_t)s * 64 + lane]);
}

__global__ __launch_bounds__(256) void gemm_relu_kernel(
    const float* __restrict__ A, const float* __restrict__ W,
    float* __restrict__ out, int n)
{
    __shared__ float Wt[64][65];
    __shared__ float rowbuf[4][64];
    int tid = threadIdx.x;
    for (int i = tid; i < 4096; i += 256) Wt[i & 63][i >> 6] = W[i];
    __syncthreads();
    int lane = tid & 63;
    int w = tid >> 6;
    int wavesTotal = gridDim.x * 4;
    for (int i = blockIdx.x * 4 + w; i < n; i += wavesTotal) {
        rowbuf[w][lane] = A[(size_t)i * 64 + lane];
        __builtin_amdgcn_wave_barrier();
        float o = 0.f;
#pragma unroll
        for (int k = 0; k < 64; ++k) o += rowbuf[w][k] * Wt[k][lane];
        out[(size_t)i * 64 + lane] = fmaxf(o, 0.f);
        __builtin_amdgcn_wave_barrier();
    }
}

__global__ __launch_bounds__(256) void final_kernel(
    const float* __restrict__ Agg, const float* __restrict__ H1,
    const float* __restrict__ W1, const float* __restrict__ Wm,
    float* __restrict__ out, int n)
{
    __shared__ float W1t[64][65];
    __shared__ float Wmt[64][65];
    __shared__ float rowbuf[4][64];
    __shared__ float selfbuf[4][64];
    int tid = threadIdx.x;
    for (int i = tid; i < 4096; i += 256) {
        W1t[i & 63][i >> 6] = W1[i];
        Wmt[i & 63][i >> 6] = Wm[i];
    }
    __syncthreads();
    int lane = tid & 63;
    int w = tid >> 6;
    int wavesTotal = gridDim.x * 4;
    for (int i = blockIdx.x * 4 + w; i < n; i += wavesTotal) {
        rowbuf[w][lane] = Agg[(size_t)i * 64 + lane];
        selfbuf[w][lane] = H1[(size_t)i * 64 + lane];
        __builtin_amdgcn_wave_barrier();
        float o1 = 0.f, o2 = 0.f;
#pragma unroll
        for (int k = 0; k < 64; ++k) {
            o1 += rowbuf[w][k] * W1t[k][lane];
            o2 += selfbuf[w][k] * Wmt[k][lane];
        }
        out[(size_t)i * 64 + lane] = (fmaxf(o1, 0.f) + o2) * 0.5f;
        __builtin_amdgcn_wave_barrier();
    }
}

// ================================================================ launch
extern "C" void kernel_launch(void* const* d_in, const int* in_sizes, int n_in,
                              void* d_out, int out_size, void* d_ws, size_t ws_size,
                              hipStream_t stream)
{
    const float* x    = (const float*)d_in[0];
    const int*   ei   = (const int*)d_in[1];
    const float* W0   = (const float*)d_in[2];
    const float* eps0 = (const float*)d_in[3];
    const float* W1   = (const float*)d_in[4];
    const float* eps1 = (const float*)d_in[5];
    const float* Wm   = (const float*)d_in[6];
    float* out = (float*)d_out;

    int n = in_sizes[0] / 64;   // 100000
    int E = in_sizes[1] / 2;    // 1600000
    const int* src = ei;
    const int* dst = ei + E;

    auto align1k = [](size_t v) { return (v + 1023) & ~(size_t)1023; };

    // ---- tier A2 layout (fp16 mirrors; ~39.3 MB)
    size_t hhx_off    = 0;
    size_t hh1_off    = align1k(hhx_off + (size_t)n * 64 * 2);
    size_t off_off    = align1k(hh1_off + (size_t)n * 64 * 2);
    size_t deg_off    = align1k(off_off + (size_t)(n + 1) * 4);
    size_t bsum_off   = align1k(deg_off + (size_t)n * 4);
    size_t bucket_off = align1k(bsum_off + 256 * 4);
    size_t rank_off   = align1k(bucket_off + (size_t)E * 4);
    size_t need_A2    = rank_off + (size_t)E * 4;

    // ---- tier B layout (fp32, cursor fill; ~33.2 MB)
    size_t b_h1_off     = 0;
    size_t b_off_off    = align1k(b_h1_off + (size_t)n * 64 * 4);
    size_t b_deg_off    = align1k(b_off_off + (size_t)(n + 1) * 4);
    size_t b_cursor_off = align1k(b_deg_off + (size_t)n * 4);
    size_t b_bsum_off   = align1k(b_cursor_off + (size_t)n * 4);
    size_t b_bucket_off = align1k(b_bsum_off + 256 * 4);
    size_t need_B       = b_bucket_off + (size_t)E * 4;

    int nb = (n + 1023) / 1024;            // <=256 required
    int e8Blocks  = (E + 2047) / 2048;
    int e16Blocks = (E + 4095) / 4096;
    int total4 = n * 16;

    if (ws_size >= need_A2) {
        __half* hhx  = (__half*)((char*)d_ws + hhx_off);
        __half* hh1  = (__half*)((char*)d_ws + hh1_off);
        int* off     = (int*)((char*)d_ws + off_off);
        int* deg     = (int*)((char*)d_ws + deg_off);
        int* bsum    = (int*)((char*)d_ws + bsum_off);
        int* bucket  = (int*)((char*)d_ws + bucket_off);
        int* rank    = (int*)((char*)d_ws + rank_off);

        zero_int_kernel<<<256, 256, 0, stream>>>(deg, n);
        f32_to_f16_kernel<<<2048, 256, 0, stream>>>(x, hhx, total4);
        hist_rank_kernel<<<e16Blocks, 256, 0, stream>>>(dst, deg, rank, E);
        scanA_kernel<<<nb, 256, 0, stream>>>(deg, off, bsum, n);
        scanB_kernel<<<1, 256, 0, stream>>>(bsum, nb);
        scanC_kernel<<<nb, 256, 0, stream>>>(off, (int*)nullptr, bsum, n, E);
        fill_rank_kernel<<<e8Blocks, 256, 0, stream>>>(src, dst, rank, off, bucket, E);

        // gin: 27.6KB LDS -> 4 blocks/CU (32 waves); grid 1024
        fused_gin_h_kernel<<<1024, 512, 0, stream>>>(hhx, off, bucket, W0, eps0, hh1, n);
        // final: 47.1KB LDS -> 3 blocks/CU; grid 768
        fused_final_h_kernel<<<768, 512, 0, stream>>>(hh1, off, bucket, W1, Wm, eps1, out, n);
    } else if (ws_size >= need_B) {
        float* h1    = (float*)((char*)d_ws + b_h1_off);
        int* off     = (int*)((char*)d_ws + b_off_off);
        int* deg     = (int*)((char*)d_ws + b_deg_off);
        int* cursor  = (int*)((char*)d_ws + b_cursor_off);
        int* bsum    = (int*)((char*)d_ws + b_bsum_off);
        int* bucket  = (int*)((char*)d_ws + b_bucket_off);

        zero_int_kernel<<<256, 256, 0, stream>>>(deg, n);
        hist_kernel<<<(E + 1023) / 1024, 256, 0, stream>>>(dst, deg, E);
        scanA_kernel<<<nb, 256, 0, stream>>>(deg, off, bsum, n);
        scanB_kernel<<<1, 256, 0, stream>>>(bsum, nb);
        scanC_kernel<<<nb, 256, 0, stream>>>(off, cursor, bsum, n, E);
        fill_kernel<<<(E + 255) / 256, 256, 0, stream>>>(src, dst, cursor, bucket, E);

        fused_gin_kernel<<<1024, 512, 0, stream>>>(x, off, bucket, W0, eps0, h1, n);
        fused_final_csr_kernel<<<768, 512, 0, stream>>>(h1, off, bucket, W1, Wm, eps1, out, n);
    } else {
        float* agg = (float*)d_ws;
        float* h1  = out;
        int scatterBlocks = (E + 3) / 4;

        init_scale_kernel<<<2048, 256, 0, stream>>>(x, eps0, agg, total4);
        scatter_kernel<<<scatterBlocks, 256, 0, stream>>>(x, src, dst, agg, E);
        gemm_relu_kernel<<<2048, 256, 0, stream>>>(agg, W0, h1, n);
        init_scale_kernel<<<2048, 256, 0, stream>>>(h1, eps1, agg, total4);
        scatter_kernel<<<scatterBlocks, 256, 0, stream>>>(h1, src, dst, agg, E);
        final_kernel<<<2048, 256, 0, stream>>>(agg, h1, W1, Wm, out, n);
    }
}

// Round 10
// 225.230 us; speedup vs baseline: 4.2147x; 1.0736x over previous
//
#include <hip/hip_runtime.h>
#include <hip/hip_fp16.h>

// GIN: h1 = relu((scatter_add(x) + (1+eps0)*x) @ W0^T)
//      h2 = relu((scatter_add(h1) + (1+eps1)*h1) @ W1^T)
//      out = (h1 @ Wm^T + h2) / 2
//
// R10: R9 showed fp16 halved FETCH (187->84MB) with NO time change -> gather
// is instruction/latency bound, not byte bound. This round halves instruction
// count on both phases:
//  - gather: 8 groups x 8 lanes x uint4(16B) = 8 edges per VMEM instr (was 4);
//    cross-group reduce via shfl_xor(8/16/32) on packed fp16 (P-LDS gone)
//  - matvec: fp16 W + fp16 row/self in LDS, v_dot2_f32_f16 (fdot2) -> 32
//    dot2/matrix vs 128 fp32 FMA; W in [k4][row] uint4 layout (conflict-free)
//  - LDS: final ~18KB, gin ~9KB -> both at the 32-wave/CU cap, final grid 1024
// CSR build + tiers B/C unchanged (R5/R6/R9-proven).

// ================================================================ CSR build
__global__ __launch_bounds__(256) void zero_int_kernel(int* __restrict__ p, int n)
{
    int i = blockIdx.x * blockDim.x + threadIdx.x;
    int stride = gridDim.x * blockDim.x;
    for (; i < n; i += stride) p[i] = 0;
}

__global__ __launch_bounds__(256) void hist_rank_kernel(
    const int* __restrict__ dst, int* __restrict__ deg,
    int* __restrict__ rank, int E)
{
    int base = (blockIdx.x * blockDim.x + threadIdx.x) * 16;
    if (base + 15 < E) {
        int4 a = *(const int4*)&dst[base];
        int4 b = *(const int4*)&dst[base + 4];
        int4 c = *(const int4*)&dst[base + 8];
        int4 d = *(const int4*)&dst[base + 12];
        int r0 = atomicAdd(&deg[a.x], 1);
        int r1 = atomicAdd(&deg[a.y], 1);
        int r2 = atomicAdd(&deg[a.z], 1);
        int r3 = atomicAdd(&deg[a.w], 1);
        int r4 = atomicAdd(&deg[b.x], 1);
        int r5 = atomicAdd(&deg[b.y], 1);
        int r6 = atomicAdd(&deg[b.z], 1);
        int r7 = atomicAdd(&deg[b.w], 1);
        int r8 = atomicAdd(&deg[c.x], 1);
        int r9 = atomicAdd(&deg[c.y], 1);
        int rA = atomicAdd(&deg[c.z], 1);
        int rB = atomicAdd(&deg[c.w], 1);
        int rC = atomicAdd(&deg[d.x], 1);
        int rD = atomicAdd(&deg[d.y], 1);
        int rE = atomicAdd(&deg[d.z], 1);
        int rF = atomicAdd(&deg[d.w], 1);
        *(int4*)&rank[base]      = make_int4(r0, r1, r2, r3);
        *(int4*)&rank[base + 4]  = make_int4(r4, r5, r6, r7);
        *(int4*)&rank[base + 8]  = make_int4(r8, r9, rA, rB);
        *(int4*)&rank[base + 12] = make_int4(rC, rD, rE, rF);
    } else {
        for (int e = base; e < E; ++e) rank[e] = atomicAdd(&deg[dst[e]], 1);
    }
}

__global__ __launch_bounds__(256) void hist_kernel(
    const int* __restrict__ dst, int* __restrict__ deg, int E)
{
    int e4 = (blockIdx.x * blockDim.x + threadIdx.x) * 4;
    if (e4 + 3 < E) {
        int4 d = *(const int4*)&dst[e4];
        atomicAdd(&deg[d.x], 1);
        atomicAdd(&deg[d.y], 1);
        atomicAdd(&deg[d.z], 1);
        atomicAdd(&deg[d.w], 1);
    } else {
        for (int e = e4; e < E; ++e) atomicAdd(&deg[dst[e]], 1);
    }
}

__global__ __launch_bounds__(256) void scanA_kernel(
    const int* __restrict__ deg, int* __restrict__ off,
    int* __restrict__ bsum, int n)
{
    __shared__ int tmp[256];
    int t = threadIdx.x;
    int base = blockIdx.x * 1024 + t * 4;
    int v0 = 0, v1 = 0, v2 = 0, v3 = 0;
    if (base + 3 < n) {
        int4 q = *(const int4*)&deg[base];
        v0 = q.x; v1 = q.y; v2 = q.z; v3 = q.w;
    } else {
        if (base + 0 < n) v0 = deg[base + 0];
        if (base + 1 < n) v1 = deg[base + 1];
        if (base + 2 < n) v2 = deg[base + 2];
    }
    int tot = v0 + v1 + v2 + v3;
    tmp[t] = tot;
    __syncthreads();
    for (int d = 1; d < 256; d <<= 1) {
        int x = (t >= d) ? tmp[t - d] : 0;
        __syncthreads();
        tmp[t] += x;
        __syncthreads();
    }
    int incl = tmp[t];
    int p = incl - tot;
    if (base + 0 < n) off[base + 0] = p;
    if (base + 1 < n) off[base + 1] = p + v0;
    if (base + 2 < n) off[base + 2] = p + v0 + v1;
    if (base + 3 < n) off[base + 3] = p + v0 + v1 + v2;
    if (t == 255) bsum[blockIdx.x] = incl;
}

__global__ __launch_bounds__(256) void scanB_kernel(int* __restrict__ bsum, int nb)
{
    __shared__ int tmp[256];
    int t = threadIdx.x;
    int v = (t < nb) ? bsum[t] : 0;
    tmp[t] = v;
    __syncthreads();
    for (int d = 1; d < 256; d <<= 1) {
        int x = (t >= d) ? tmp[t - d] : 0;
        __syncthreads();
        tmp[t] += x;
        __syncthreads();
    }
    if (t < nb) bsum[t] = tmp[t] - v;
}

__global__ __launch_bounds__(256) void scanC_kernel(
    int* __restrict__ off, int* __restrict__ cursor,
    const int* __restrict__ bsum, int n, int E)
{
    int t = threadIdx.x;
    int add = bsum[blockIdx.x];
    int base = blockIdx.x * 1024 + t * 4;
#pragma unroll
    for (int q = 0; q < 4; ++q) {
        int idx = base + q;
        if (idx < n) {
            int v = off[idx] + add;
            off[idx] = v;
            if (cursor) cursor[idx] = v;
        }
    }
    if (blockIdx.x == 0 && t == 0) off[n] = E;
}

__global__ __launch_bounds__(256) void fill_rank_kernel(
    const int* __restrict__ src, const int* __restrict__ dst,
    const int* __restrict__ rank, const int* __restrict__ off,
    int* __restrict__ bucket, int E)
{
    int base = (blockIdx.x * blockDim.x + threadIdx.x) * 8;
    if (base + 7 < E) {
        int4 d0 = *(const int4*)&dst[base];
        int4 d1 = *(const int4*)&dst[base + 4];
        int4 r0 = *(const int4*)&rank[base];
        int4 r1 = *(const int4*)&rank[base + 4];
        int4 s0 = *(const int4*)&src[base];
        int4 s1 = *(const int4*)&src[base + 4];
        bucket[off[d0.x] + r0.x] = s0.x;
        bucket[off[d0.y] + r0.y] = s0.y;
        bucket[off[d0.z] + r0.z] = s0.z;
        bucket[off[d0.w] + r0.w] = s0.w;
        bucket[off[d1.x] + r1.x] = s1.x;
        bucket[off[d1.y] + r1.y] = s1.y;
        bucket[off[d1.z] + r1.z] = s1.z;
        bucket[off[d1.w] + r1.w] = s1.w;
    } else {
        for (int e = base; e < E; ++e) bucket[off[dst[e]] + rank[e]] = src[e];
    }
}

__global__ __launch_bounds__(256) void fill_kernel(
    const int* __restrict__ src, const int* __restrict__ dst,
    int* __restrict__ cursor, int* __restrict__ bucket, int E)
{
    int e = blockIdx.x * blockDim.x + threadIdx.x;
    if (e < E) {
        int d = dst[e];
        int p = atomicAdd(&cursor[d], 1);
        bucket[p] = src[e];
    }
}

// ================================================================ fp32 -> fp16 convert
__global__ __launch_bounds__(256) void f32_to_f16_kernel(
    const float* __restrict__ in, __half* __restrict__ out, int total4)
{
    int i = blockIdx.x * blockDim.x + threadIdx.x;
    int stride = gridDim.x * blockDim.x;
    const float4* in4 = (const float4*)in;
    uint2* out4 = (uint2*)out;
    for (; i < total4; i += stride) {
        float4 v = in4[i];
        __half2 a = __floats2half2_rn(v.x, v.y);
        __half2 b = __floats2half2_rn(v.z, v.w);
        uint2 u;
        u.x = __builtin_bit_cast(unsigned int, a);
        u.y = __builtin_bit_cast(unsigned int, b);
        out4[i] = u;
    }
}

// ================================================================ helpers
#define WPB 8  // waves per 512-thread block

__device__ __forceinline__ __half2 bc_h2(unsigned int u)
{
    return __builtin_bit_cast(__half2, u);
}
__device__ __forceinline__ unsigned int bc_u(__half2 h)
{
    return __builtin_bit_cast(unsigned int, h);
}

#if __has_builtin(__builtin_amdgcn_fdot2)
typedef _Float16 half2_v __attribute__((ext_vector_type(2)));
__device__ __forceinline__ float fdot2(unsigned int a, unsigned int b, float c)
{
    return __builtin_amdgcn_fdot2(__builtin_bit_cast(half2_v, a),
                                  __builtin_bit_cast(half2_v, b), c, false);
}
#else
__device__ __forceinline__ float fdot2(unsigned int a, unsigned int b, float c)
{
    float2 af = __half22float2(bc_h2(a));
    float2 bf = __half22float2(bc_h2(b));
    return fmaf(af.x, bf.x, fmaf(af.y, bf.y, c));
}
#endif

// cross-group (8 groups of 8 lanes) packed-fp16 reduce of 4 half2 words
__device__ __forceinline__ void xreduce4(__half2& a0, __half2& a1,
                                         __half2& a2, __half2& a3)
{
#pragma unroll
    for (int mask = 8; mask <= 32; mask <<= 1) {
        a0 = __hadd2(a0, bc_h2((unsigned int)__shfl_xor((int)bc_u(a0), mask, 64)));
        a1 = __hadd2(a1, bc_h2((unsigned int)__shfl_xor((int)bc_u(a1), mask, 64)));
        a2 = __hadd2(a2, bc_h2((unsigned int)__shfl_xor((int)bc_u(a2), mask, 64)));
        a3 = __hadd2(a3, bc_h2((unsigned int)__shfl_xor((int)bc_u(a3), mask, 64)));
    }
}

// gather one node's row: 8 groups x 8 lanes, uint4 (8 fp16) per lane.
// Returns packed accumulators (pre-reduction) in a0..a3.
__device__ __forceinline__ void gather8(
    const __half* __restrict__ hh, const int* __restrict__ bucket,
    int beg, int end, int g, int l8,
    __half2& a0, __half2& a1, __half2& a2, __half2& a3)
{
    int j = beg;
    for (; j + 16 <= end; j += 16) {
        int sa = bucket[j + g];
        int sb = bucket[j + 8 + g];
        uint4 va = *(const uint4*)&hh[(size_t)sa * 64 + l8 * 8];
        uint4 vb = *(const uint4*)&hh[(size_t)sb * 64 + l8 * 8];
        a0 = __hadd2(__hadd2(a0, bc_h2(va.x)), bc_h2(vb.x));
        a1 = __hadd2(__hadd2(a1, bc_h2(va.y)), bc_h2(vb.y));
        a2 = __hadd2(__hadd2(a2, bc_h2(va.z)), bc_h2(vb.z));
        a3 = __hadd2(__hadd2(a3, bc_h2(va.w)), bc_h2(vb.w));
    }
    if (j + 8 <= end) {
        int sa = bucket[j + g];
        uint4 va = *(const uint4*)&hh[(size_t)sa * 64 + l8 * 8];
        a0 = __hadd2(a0, bc_h2(va.x));
        a1 = __hadd2(a1, bc_h2(va.y));
        a2 = __hadd2(a2, bc_h2(va.z));
        a3 = __hadd2(a3, bc_h2(va.w));
        j += 8;
    }
    if (j < end) {  // 1..7 tail edges, masked
        int jj = j + g;
        int sc = bucket[(jj < end) ? jj : (end - 1)];
        __half2 m2 = __float2half2_rn((jj < end) ? 1.0f : 0.0f);
        uint4 vc = *(const uint4*)&hh[(size_t)sc * 64 + l8 * 8];
        a0 = __hfma2(bc_h2(vc.x), m2, a0);
        a1 = __hfma2(bc_h2(vc.y), m2, a1);
        a2 = __hfma2(bc_h2(vc.z), m2, a2);
        a3 = __hfma2(bc_h2(vc.w), m2, a3);
    }
}

// ================================================================ tier A fused kernels
// W LDS layout: flat fp16, index(k4,row,e) = k4*512 + row*8 + e; read as
// uint4 at [k4*64 + row] -> 16B/lane, 1KB/wave contiguous: conflict-free.

__global__ __launch_bounds__(512) void fused_gin_h_kernel(
    const __half* __restrict__ hh, const int* __restrict__ off,
    const int* __restrict__ bucket, const float* __restrict__ W,
    const float* __restrict__ eps, __half* __restrict__ outh, int n)
{
    __shared__ __half WhS[4096];       // [k4][row][e] fp16
    __shared__ __half rowh[WPB][64];
    int tid = threadIdx.x;
    for (int idx = tid; idx < 4096; idx += 512) {
        int row = idx >> 6, col = idx & 63;
        WhS[(col >> 3) * 512 + row * 8 + (col & 7)] = __float2half(W[idx]);
    }
    __syncthreads();
    float s = 1.0f + eps[0];
    __half2 s2 = __float2half2_rn(s);
    int lane = tid & 63;
    int w = tid >> 6;
    int l8 = lane & 7;
    int g = lane >> 3;
    int wavesTotal = gridDim.x * WPB;
    const uint4* Wh4 = (const uint4*)WhS;
    for (int i = blockIdx.x * WPB + w; i < n; i += wavesTotal) {
        int2 be = *(const int2*)&off[i];
        int beg = __builtin_amdgcn_readfirstlane(be.x);
        int end = __builtin_amdgcn_readfirstlane(be.y);
        __half2 a0 = bc_h2(0u), a1 = bc_h2(0u), a2 = bc_h2(0u), a3 = bc_h2(0u);
        gather8(hh, bucket, beg, end, g, l8, a0, a1, a2, a3);
        xreduce4(a0, a1, a2, a3);
        if (g == 0) {  // add (1+eps)*self, store row (lanes 0..7 cover 64ch)
            uint4 sv = *(const uint4*)&hh[(size_t)i * 64 + l8 * 8];
            a0 = __hfma2(bc_h2(sv.x), s2, a0);
            a1 = __hfma2(bc_h2(sv.y), s2, a1);
            a2 = __hfma2(bc_h2(sv.z), s2, a2);
            a3 = __hfma2(bc_h2(sv.w), s2, a3);
            uint4 st;
            st.x = bc_u(a0); st.y = bc_u(a1); st.z = bc_u(a2); st.w = bc_u(a3);
            *(uint4*)&rowh[w][l8 * 8] = st;
        }
        __builtin_amdgcn_wave_barrier();
        float o = 0.f;
#pragma unroll
        for (int k4 = 0; k4 < 8; ++k4) {
            uint4 wv = Wh4[k4 * 64 + lane];
            uint4 rv = *(const uint4*)&rowh[w][k4 * 8];
            o = fdot2(wv.x, rv.x, o);
            o = fdot2(wv.y, rv.y, o);
            o = fdot2(wv.z, rv.z, o);
            o = fdot2(wv.w, rv.w, o);
        }
        outh[(size_t)i * 64 + lane] = __float2half(fmaxf(o, 0.f));
        __builtin_amdgcn_wave_barrier();
    }
}

__global__ __launch_bounds__(512) void fused_final_h_kernel(
    const __half* __restrict__ hh1, const int* __restrict__ off,
    const int* __restrict__ bucket, const float* __restrict__ W1,
    const float* __restrict__ Wm, const float* __restrict__ eps,
    float* __restrict__ out, int n)
{
    __shared__ __half W1hS[4096];
    __shared__ __half WmhS[4096];
    __shared__ __half rowh[WPB][64];
    __shared__ __half selfh[WPB][64];
    int tid = threadIdx.x;
    for (int idx = tid; idx < 4096; idx += 512) {
        int row = idx >> 6, col = idx & 63;
        int li = (col >> 3) * 512 + row * 8 + (col & 7);
        W1hS[li] = __float2half(W1[idx]);
        WmhS[li] = __float2half(Wm[idx]);
    }
    __syncthreads();
    float s = 1.0f + eps[0];
    __half2 s2 = __float2half2_rn(s);
    int lane = tid & 63;
    int w = tid >> 6;
    int l8 = lane & 7;
    int g = lane >> 3;
    int wavesTotal = gridDim.x * WPB;
    const uint4* W1h4 = (const uint4*)W1hS;
    const uint4* Wmh4 = (const uint4*)WmhS;
    for (int i = blockIdx.x * WPB + w; i < n; i += wavesTotal) {
        int2 be = *(const int2*)&off[i];
        int beg = __builtin_amdgcn_readfirstlane(be.x);
        int end = __builtin_amdgcn_readfirstlane(be.y);
        __half2 a0 = bc_h2(0u), a1 = bc_h2(0u), a2 = bc_h2(0u), a3 = bc_h2(0u);
        gather8(hh1, bucket, beg, end, g, l8, a0, a1, a2, a3);
        xreduce4(a0, a1, a2, a3);
        if (g == 0) {  // stash self, add (1+eps)*self, store row
            uint4 sv = *(const uint4*)&hh1[(size_t)i * 64 + l8 * 8];
            *(uint4*)&selfh[w][l8 * 8] = sv;
            a0 = __hfma2(bc_h2(sv.x), s2, a0);
            a1 = __hfma2(bc_h2(sv.y), s2, a1);
            a2 = __hfma2(bc_h2(sv.z), s2, a2);
            a3 = __hfma2(bc_h2(sv.w), s2, a3);
            uint4 st;
            st.x = bc_u(a0); st.y = bc_u(a1); st.z = bc_u(a2); st.w = bc_u(a3);
            *(uint4*)&rowh[w][l8 * 8] = st;
        }
        __builtin_amdgcn_wave_barrier();
        float o1 = 0.f, o2 = 0.f;
#pragma unroll
        for (int k4 = 0; k4 < 8; ++k4) {
            uint4 wv1 = W1h4[k4 * 64 + lane];
            uint4 wv2 = Wmh4[k4 * 64 + lane];
            uint4 rv  = *(const uint4*)&rowh[w][k4 * 8];
            uint4 sv  = *(const uint4*)&selfh[w][k4 * 8];
            o1 = fdot2(wv1.x, rv.x, o1);
            o1 = fdot2(wv1.y, rv.y, o1);
            o1 = fdot2(wv1.z, rv.z, o1);
            o1 = fdot2(wv1.w, rv.w, o1);
            o2 = fdot2(wv2.x, sv.x, o2);
            o2 = fdot2(wv2.y, sv.y, o2);
            o2 = fdot2(wv2.z, sv.z, o2);
            o2 = fdot2(wv2.w, sv.w, o2);
        }
        out[(size_t)i * 64 + lane] = (fmaxf(o1, 0.f) + o2) * 0.5f;
        __builtin_amdgcn_wave_barrier();
    }
}

// ================================================================ tier B: fp32 fused (R6-proven)
__device__ __forceinline__ float dot4(float4 a, float4 b)
{
    return a.x * b.x + a.y * b.y + a.z * b.z + a.w * b.w;
}

__device__ __forceinline__ float4 gather_row_f32(
    const float* __restrict__ h, const int* __restrict__ bucket,
    int beg, int end, int g, int l16, float4 acc4)
{
    int j = beg;
    for (; j + 8 <= end; j += 8) {
        int sa = bucket[j + g];
        int sb = bucket[j + 4 + g];
        float4 va = *(const float4*)&h[(size_t)sa * 64 + l16 * 4];
        float4 vb = *(const float4*)&h[(size_t)sb * 64 + l16 * 4];
        acc4.x += va.x + vb.x;
        acc4.y += va.y + vb.y;
        acc4.z += va.z + vb.z;
        acc4.w += va.w + vb.w;
    }
    if (j + 4 <= end) {
        int sa = bucket[j + g];
        float4 va = *(const float4*)&h[(size_t)sa * 64 + l16 * 4];
        acc4.x += va.x; acc4.y += va.y; acc4.z += va.z; acc4.w += va.w;
        j += 4;
    }
    if (j < end) {
        int jj = j + g;
        int sc = bucket[(jj < end) ? jj : (end - 1)];
        float m = (jj < end) ? 1.0f : 0.0f;
        float4 vc = *(const float4*)&h[(size_t)sc * 64 + l16 * 4];
        acc4.x = fmaf(vc.x, m, acc4.x);
        acc4.y = fmaf(vc.y, m, acc4.y);
        acc4.z = fmaf(vc.z, m, acc4.z);
        acc4.w = fmaf(vc.w, m, acc4.w);
    }
    return acc4;
}

__global__ __launch_bounds__(512) void fused_gin_kernel(
    const float* __restrict__ h, const int* __restrict__ off,
    const int* __restrict__ bucket, const float* __restrict__ W,
    const float* __restrict__ eps, float* __restrict__ out, int n)
{
    __shared__ float Ws[64][68];
    __shared__ float P[WPB][4][64];
    __shared__ float rowbuf[WPB][64];
    int tid = threadIdx.x;
    for (int idx = tid; idx < 4096; idx += 512) Ws[idx >> 6][idx & 63] = W[idx];
    __syncthreads();
    float s = 1.0f + eps[0];
    int lane = tid & 63;
    int w = tid >> 6;
    int l16 = lane & 15;
    int g = lane >> 4;
    int wavesTotal = gridDim.x * WPB;
    for (int i = blockIdx.x * WPB + w; i < n; i += wavesTotal) {
        float4 init = make_float4(0.f, 0.f, 0.f, 0.f);
        if (g == 0) {
            float4 self4 = *(const float4*)&h[(size_t)i * 64 + l16 * 4];
            init = make_float4(s * self4.x, s * self4.y, s * self4.z, s * self4.w);
        }
        int2 be = *(const int2*)&off[i];
        int beg = __builtin_amdgcn_readfirstlane(be.x);
        int end = __builtin_amdgcn_readfirstlane(be.y);
        float4 acc4 = gather_row_f32(h, bucket, beg, end, g, l16, init);
        *(float4*)&P[w][g][l16 * 4] = acc4;
        __builtin_amdgcn_wave_barrier();
        float r0 = P[w][0][lane], r1 = P[w][1][lane];
        float r2 = P[w][2][lane], r3 = P[w][3][lane];
        rowbuf[w][lane] = (r0 + r1) + (r2 + r3);
        __builtin_amdgcn_wave_barrier();
        const float4* wrow = (const float4*)&Ws[lane][0];
        const float4* rrow = (const float4*)&rowbuf[w][0];
        float o = 0.f;
#pragma unroll
        for (int k4 = 0; k4 < 16; ++k4) o += dot4(wrow[k4], rrow[k4]);
        out[(size_t)i * 64 + lane] = fmaxf(o, 0.f);
        __builtin_amdgcn_wave_barrier();
    }
}

__global__ __launch_bounds__(512) void fused_final_csr_kernel(
    const float* __restrict__ h1, const int* __restrict__ off,
    const int* __restrict__ bucket, const float* __restrict__ W1,
    const float* __restrict__ Wm, const float* __restrict__ eps,
    float* __restrict__ out, int n)
{
    __shared__ float W1s[64][68];
    __shared__ float Wms[64][68];
    __shared__ float P[WPB][4][64];
    __shared__ float rowbuf[WPB][64];
    __shared__ float selfbuf[WPB][64];
    int tid = threadIdx.x;
    for (int idx = tid; idx < 4096; idx += 512) {
        W1s[idx >> 6][idx & 63] = W1[idx];
        Wms[idx >> 6][idx & 63] = Wm[idx];
    }
    __syncthreads();
    float s = 1.0f + eps[0];
    int lane = tid & 63;
    int w = tid >> 6;
    int l16 = lane & 15;
    int g = lane >> 4;
    int wavesTotal = gridDim.x * WPB;
    for (int i = blockIdx.x * WPB + w; i < n; i += wavesTotal) {
        float4 init = make_float4(0.f, 0.f, 0.f, 0.f);
        if (g == 0) {
            float4 self4 = *(const float4*)&h1[(size_t)i * 64 + l16 * 4];
            *(float4*)&selfbuf[w][l16 * 4] = self4;
            init = make_float4(s * self4.x, s * self4.y, s * self4.z, s * self4.w);
        }
        int2 be = *(const int2*)&off[i];
        int beg = __builtin_amdgcn_readfirstlane(be.x);
        int end = __builtin_amdgcn_readfirstlane(be.y);
        float4 acc4 = gather_row_f32(h1, bucket, beg, end, g, l16, init);
        *(float4*)&P[w][g][l16 * 4] = acc4;
        __builtin_amdgcn_wave_barrier();
        float r0 = P[w][0][lane], r1 = P[w][1][lane];
        float r2 = P[w][2][lane], r3 = P[w][3][lane];
        rowbuf[w][lane] = (r0 + r1) + (r2 + r3);
        __builtin_amdgcn_wave_barrier();
        const float4* w1row = (const float4*)&W1s[lane][0];
        const float4* wmrow = (const float4*)&Wms[lane][0];
        const float4* rrow  = (const float4*)&rowbuf[w][0];
        const float4* srow  = (const float4*)&selfbuf[w][0];
        float o1 = 0.f, o2 = 0.f;
#pragma unroll
        for (int k4 = 0; k4 < 16; ++k4) {
            o1 += dot4(w1row[k4], rrow[k4]);
            o2 += dot4(wmrow[k4], srow[k4]);
        }
        out[(size_t)i * 64 + lane] = (fmaxf(o1, 0.f) + o2) * 0.5f;
        __builtin_amdgcn_wave_barrier();
    }
}

// ================================================================ tier C: atomic scatter
__global__ __launch_bounds__(256) void init_scale_kernel(
    const float* __restrict__ h, const float* __restrict__ eps,
    float* __restrict__ agg, int total4)
{
    float s = 1.0f + eps[0];
    int i = blockIdx.x * blockDim.x + threadIdx.x;
    int stride = gridDim.x * blockDim.x;
    const float4* h4 = (const float4*)h;
    float4* a4 = (float4*)agg;
    for (; i < total4; i += stride) {
        float4 v = h4[i];
        v.x *= s; v.y *= s; v.z *= s; v.w *= s;
        a4[i] = v;
    }
}

__global__ __launch_bounds__(256) void scatter_kernel(
    const float* __restrict__ h, const int* __restrict__ src,
    const int* __restrict__ dst, float* __restrict__ agg, int E)
{
    int lane = threadIdx.x & 63;
    int e = blockIdx.x * 4 + (threadIdx.x >> 6);
    if (e >= E) return;
    int s = src[e];
    int d = dst[e];
    atomicAdd(&agg[(size_t)d * 64 + lane], h[(size_t)s * 64 + lane]);
}

__global__ __launch_bounds__(256) void gemm_relu_kernel(
    const float* __restrict__ A, const float* __restrict__ W,
    float* __restrict__ out, int n)
{
    __shared__ float Wt[64][65];
    __shared__ float rowbuf[4][64];
    int tid = threadIdx.x;
    for (int i = tid; i < 4096; i += 256) Wt[i & 63][i >> 6] = W[i];
    __syncthreads();
    int lane = tid & 63;
    int w = tid >> 6;
    int wavesTotal = gridDim.x * 4;
    for (int i = blockIdx.x * 4 + w; i < n; i += wavesTotal) {
        rowbuf[w][lane] = A[(size_t)i * 64 + lane];
        __builtin_amdgcn_wave_barrier();
        float o = 0.f;
#pragma unroll
        for (int k = 0; k < 64; ++k) o += rowbuf[w][k] * Wt[k][lane];
        out[(size_t)i * 64 + lane] = fmaxf(o, 0.f);
        __builtin_amdgcn_wave_barrier();
    }
}

__global__ __launch_bounds__(256) void final_kernel(
    const float* __restrict__ Agg, const float* __restrict__ H1,
    const float* __restrict__ W1, const float* __restrict__ Wm,
    float* __restrict__ out, int n)
{
    __shared__ float W1t[64][65];
    __shared__ float Wmt[64][65];
    __shared__ float rowbuf[4][64];
    __shared__ float selfbuf[4][64];
    int tid = threadIdx.x;
    for (int i = tid; i < 4096; i += 256) {
        W1t[i & 63][i >> 6] = W1[i];
        Wmt[i & 63][i >> 6] = Wm[i];
    }
    __syncthreads();
    int lane = tid & 63;
    int w = tid >> 6;
    int wavesTotal = gridDim.x * 4;
    for (int i = blockIdx.x * 4 + w; i < n; i += wavesTotal) {
        rowbuf[w][lane] = Agg[(size_t)i * 64 + lane];
        selfbuf[w][lane] = H1[(size_t)i * 64 + lane];
        __builtin_amdgcn_wave_barrier();
        float o1 = 0.f, o2 = 0.f;
#pragma unroll
        for (int k = 0; k < 64; ++k) {
            o1 += rowbuf[w][k] * W1t[k][lane];
            o2 += selfbuf[w][k] * Wmt[k][lane];
        }
        out[(size_t)i * 64 + lane] = (fmaxf(o1, 0.f) + o2) * 0.5f;
        __builtin_amdgcn_wave_barrier();
    }
}

// ================================================================ launch
extern "C" void kernel_launch(void* const* d_in, const int* in_sizes, int n_in,
                              void* d_out, int out_size, void* d_ws, size_t ws_size,
                              hipStream_t stream)
{
    const float* x    = (const float*)d_in[0];
    const int*   ei   = (const int*)d_in[1];
    const float* W0   = (const float*)d_in[2];
    const float* eps0 = (const float*)d_in[3];
    const float* W1   = (const float*)d_in[4];
    const float* eps1 = (const float*)d_in[5];
    const float* Wm   = (const float*)d_in[6];
    float* out = (float*)d_out;

    int n = in_sizes[0] / 64;   // 100000
    int E = in_sizes[1] / 2;    // 1600000
    const int* src = ei;
    const int* dst = ei + E;

    auto align1k = [](size_t v) { return (v + 1023) & ~(size_t)1023; };

    // ---- tier A layout (fp16 mirrors; ~39.3 MB)
    size_t hhx_off    = 0;
    size_t hh1_off    = align1k(hhx_off + (size_t)n * 64 * 2);
    size_t off_off    = align1k(hh1_off + (size_t)n * 64 * 2);
    size_t deg_off    = align1k(off_off + (size_t)(n + 1) * 4);
    size_t bsum_off   = align1k(deg_off + (size_t)n * 4);
    size_t bucket_off = align1k(bsum_off + 256 * 4);
    size_t rank_off   = align1k(bucket_off + (size_t)E * 4);
    size_t need_A2    = rank_off + (size_t)E * 4;

    // ---- tier B layout (fp32, cursor fill; ~33.2 MB)
    size_t b_h1_off     = 0;
    size_t b_off_off    = align1k(b_h1_off + (size_t)n * 64 * 4);
    size_t b_deg_off    = align1k(b_off_off + (size_t)(n + 1) * 4);
    size_t b_cursor_off = align1k(b_deg_off + (size_t)n * 4);
    size_t b_bsum_off   = align1k(b_cursor_off + (size_t)n * 4);
    size_t b_bucket_off = align1k(b_bsum_off + 256 * 4);
    size_t need_B       = b_bucket_off + (size_t)E * 4;

    int nb = (n + 1023) / 1024;            // <=256 required
    int e8Blocks  = (E + 2047) / 2048;
    int e16Blocks = (E + 4095) / 4096;
    int total4 = n * 16;

    if (ws_size >= need_A2) {
        __half* hhx  = (__half*)((char*)d_ws + hhx_off);
        __half* hh1  = (__half*)((char*)d_ws + hh1_off);
        int* off     = (int*)((char*)d_ws + off_off);
        int* deg     = (int*)((char*)d_ws + deg_off);
        int* bsum    = (int*)((char*)d_ws + bsum_off);
        int* bucket  = (int*)((char*)d_ws + bucket_off);
        int* rank    = (int*)((char*)d_ws + rank_off);

        zero_int_kernel<<<256, 256, 0, stream>>>(deg, n);
        f32_to_f16_kernel<<<2048, 256, 0, stream>>>(x, hhx, total4);
        hist_rank_kernel<<<e16Blocks, 256, 0, stream>>>(dst, deg, rank, E);
        scanA_kernel<<<nb, 256, 0, stream>>>(deg, off, bsum, n);
        scanB_kernel<<<1, 256, 0, stream>>>(bsum, nb);
        scanC_kernel<<<nb, 256, 0, stream>>>(off, (int*)nullptr, bsum, n, E);
        fill_rank_kernel<<<e8Blocks, 256, 0, stream>>>(src, dst, rank, off, bucket, E);

        // gin: ~9.2KB LDS -> 4 blocks/CU (32 waves); grid 1024
        fused_gin_h_kernel<<<1024, 512, 0, stream>>>(hhx, off, bucket, W0, eps0, hh1, n);
        // final: ~18.4KB LDS -> 4 blocks/CU (32 waves); grid 1024
        fused_final_h_kernel<<<1024, 512, 0, stream>>>(hh1, off, bucket, W1, Wm, eps1, out, n);
    } else if (ws_size >= need_B) {
        float* h1    = (float*)((char*)d_ws + b_h1_off);
        int* off     = (int*)((char*)d_ws + b_off_off);
        int* deg     = (int*)((char*)d_ws + b_deg_off);
        int* cursor  = (int*)((char*)d_ws + b_cursor_off);
        int* bsum    = (int*)((char*)d_ws + b_bsum_off);
        int* bucket  = (int*)((char*)d_ws + b_bucket_off);

        zero_int_kernel<<<256, 256, 0, stream>>>(deg, n);
        hist_kernel<<<(E + 1023) / 1024, 256, 0, stream>>>(dst, deg, E);
        scanA_kernel<<<nb, 256, 0, stream>>>(deg, off, bsum, n);
        scanB_kernel<<<1, 256, 0, stream>>>(bsum, nb);
        scanC_kernel<<<nb, 256, 0, stream>>>(off, cursor, bsum, n, E);
        fill_kernel<<<(E + 255) / 256, 256, 0, stream>>>(src, dst, cursor, bucket, E);

        fused_gin_kernel<<<1024, 512, 0, stream>>>(x, off, bucket, W0, eps0, h1, n);
        fused_final_csr_kernel<<<768, 512, 0, stream>>>(h1, off, bucket, W1, Wm, eps1, out, n);
    } else {
        float* agg = (float*)d_ws;
        float* h1  = out;
        int scatterBlocks = (E + 3) / 4;

        init_scale_kernel<<<2048, 256, 0, stream>>>(x, eps0, agg, total4);
        scatter_kernel<<<scatterBlocks, 256, 0, stream>>>(x, src, dst, agg, E);
        gemm_relu_kernel<<<2048, 256, 0, stream>>>(agg, W0, h1, n);
        init_scale_kernel<<<2048, 256, 0, stream>>>(h1, eps1, agg, total4);
        scatter_kernel<<<scatterBlocks, 256, 0, stream>>>(h1, src, dst, agg, E);
        final_kernel<<<2048, 256, 0, stream>>>(agg, h1, W1, Wm, out, n);
    }
}